// Round 2
// baseline (3204.506 us; speedup 1.0000x reference)
//
#include <hip/hip_runtime.h>
#include <hip/hip_bf16.h>

#define NVOX (64*64*64)      // 262144 = 2^18
#define NB32 (32*NVOX)       // 2^23 floats per image of 32-ch volume

// ---------------------------------------------------------------------------
// prep: transpose conv weights [co][ci][tap] -> [ci*27+tap][co], zero stats
// ---------------------------------------------------------------------------
__global__ __launch_bounds__(256) void prep_kernel(
    const float* __restrict__ w1, const float* __restrict__ w2,
    float* __restrict__ wT1, float* __restrict__ wT2, float* __restrict__ stats)
{
    if (blockIdx.x == 0 && threadIdx.x < 48) stats[threadIdx.x] = 0.f;
    int i = blockIdx.x * 256 + threadIdx.x;
    if (i < 32 * 32 * 27) {
        int co = i / 864;          // 864 = 32*27
        int r  = i - co * 864;     // ci*27 + tap
        wT1[r * 32 + co] = w1[i];
        wT2[r * 32 + co] = w2[i];
    }
}

// ---------------------------------------------------------------------------
// 3x3x3 conv, 32->32, zero pad, + bias, + per-group (sum, sumsq) stats
// grid: (512, 2 images) x 256 thr; each thread does 2 voxels
// ---------------------------------------------------------------------------
__global__ __launch_bounds__(256) void conv3_kernel(
    const float* __restrict__ in0, const float* __restrict__ in1,
    const float* __restrict__ wT, const float* __restrict__ bias,
    float* __restrict__ out, float* __restrict__ stats, int layer)
{
    const int img = blockIdx.y;
    const float* __restrict__ in = img ? in1 : in0;
    const int t  = threadIdx.x;
    const int v0 = blockIdx.x * 512 + t;
    const int v1 = v0 + 256;
    const int h0 = v0 >> 12, w0 = (v0 >> 6) & 63, d0 = v0 & 63;
    const int h1 = v1 >> 12, w1_ = (v1 >> 6) & 63, d1 = v1 & 63;

    float acc0[32], acc1[32];
#pragma unroll
    for (int c = 0; c < 32; ++c) { acc0[c] = 0.f; acc1[c] = 0.f; }

    for (int ci = 0; ci < 32; ++ci) {
        const float* __restrict__ xci = in + ci * NVOX;
        float p0[27], p1[27];
#pragma unroll
        for (int ih = 0; ih < 3; ++ih)
#pragma unroll
        for (int iw = 0; iw < 3; ++iw)
#pragma unroll
        for (int id = 0; id < 3; ++id) {
            const int tap = (ih * 3 + iw) * 3 + id;
            {
                int hh = h0 + ih - 1, ww = w0 + iw - 1, dd = d0 + id - 1;
                bool ok = ((unsigned)hh < 64u) && ((unsigned)ww < 64u) && ((unsigned)dd < 64u);
                p0[tap] = ok ? xci[(hh << 12) + (ww << 6) + dd] : 0.f;
            }
            {
                int hh = h1 + ih - 1, ww = w1_ + iw - 1, dd = d1 + id - 1;
                bool ok = ((unsigned)hh < 64u) && ((unsigned)ww < 64u) && ((unsigned)dd < 64u);
                p1[tap] = ok ? xci[(hh << 12) + (ww << 6) + dd] : 0.f;
            }
        }
#pragma unroll
        for (int tap = 0; tap < 27; ++tap) {
            const float* __restrict__ wr = wT + (ci * 27 + tap) * 32;  // wave-uniform
#pragma unroll
            for (int q = 0; q < 32; q += 4) {
                const float4 wv = *reinterpret_cast<const float4*>(wr + q);
                acc0[q + 0] += wv.x * p0[tap]; acc0[q + 1] += wv.y * p0[tap];
                acc0[q + 2] += wv.z * p0[tap]; acc0[q + 3] += wv.w * p0[tap];
                acc1[q + 0] += wv.x * p1[tap]; acc1[q + 1] += wv.y * p1[tap];
                acc1[q + 2] += wv.z * p1[tap]; acc1[q + 3] += wv.w * p1[tap];
            }
        }
    }

    float gsum[4] = {0, 0, 0, 0}, gsq[4] = {0, 0, 0, 0};
    float* __restrict__ outi = out + (size_t)img * NB32;
#pragma unroll
    for (int co = 0; co < 32; ++co) {
        const float b  = bias[co];
        const float x0 = acc0[co] + b, x1 = acc1[co] + b;
        outi[co * NVOX + v0] = x0;
        outi[co * NVOX + v1] = x1;
        const int g = co >> 3;
        gsum[g] += x0 + x1;
        gsq[g]  += x0 * x0 + x1 * x1;
    }

    __shared__ float red[4][8];
    const int lane = t & 63, wid = t >> 6;
#pragma unroll
    for (int g = 0; g < 4; ++g) {
        float s = gsum[g], q = gsq[g];
#pragma unroll
        for (int off = 32; off > 0; off >>= 1) {
            s += __shfl_down(s, off, 64);
            q += __shfl_down(q, off, 64);
        }
        if (lane == 0) { red[wid][2 * g] = s; red[wid][2 * g + 1] = q; }
    }
    __syncthreads();
    if (t < 8) {
        float s = red[0][t] + red[1][t] + red[2][t] + red[3][t];
        atomicAdd(&stats[img * 24 + layer * 8 + t], s);
    }
}

// ---------------------------------------------------------------------------
// GroupNorm apply + leaky relu, in place, layer 0 stats
// ---------------------------------------------------------------------------
__global__ __launch_bounds__(256) void gn_lrelu_kernel(
    float* __restrict__ A, const float* __restrict__ stats,
    const float* __restrict__ gamma, const float* __restrict__ beta)
{
    const float Minv = 1.f / (8.f * (float)NVOX);
    const int total4 = (2 * NB32) / 4;
    for (int i4 = blockIdx.x * blockDim.x + threadIdx.x; i4 < total4;
         i4 += gridDim.x * blockDim.x) {
        const int i   = i4 * 4;
        const int img = i >> 23;
        const int c   = (i >> 18) & 31;
        const int g   = c >> 3;
        const float sum = stats[img * 24 + 2 * g], sq = stats[img * 24 + 2 * g + 1];
        const float mu = sum * Minv;
        const float rs = rsqrtf(sq * Minv - mu * mu + 1e-5f);
        const float sc = rs * gamma[c];
        const float sh = beta[c] - mu * sc;
        float4 vv = *reinterpret_cast<float4*>(A + i);
        float o0 = vv.x * sc + sh, o1 = vv.y * sc + sh, o2 = vv.z * sc + sh, o3 = vv.w * sc + sh;
        vv.x = o0 >= 0.f ? o0 : 0.2f * o0;
        vv.y = o1 >= 0.f ? o1 : 0.2f * o1;
        vv.z = o2 >= 0.f ? o2 : 0.2f * o2;
        vv.w = o3 >= 0.f ? o3 : 0.2f * o3;
        *reinterpret_cast<float4*>(A + i) = vv;
    }
}

// ---------------------------------------------------------------------------
// 1x1 skip conv 32->32 + bias + stats (layer 2)
// ---------------------------------------------------------------------------
__global__ __launch_bounds__(256) void skip_kernel(
    const float* __restrict__ in0, const float* __restrict__ in1,
    const float* __restrict__ wsw, const float* __restrict__ bsb,
    float* __restrict__ out, float* __restrict__ stats)
{
    const int img = blockIdx.y;
    const float* __restrict__ x = img ? in1 : in0;
    const int t = threadIdx.x;
    const int v = blockIdx.x * 256 + t;
    float xv[32];
#pragma unroll
    for (int ci = 0; ci < 32; ++ci) xv[ci] = x[ci * NVOX + v];
    float gsum[4] = {0, 0, 0, 0}, gsq[4] = {0, 0, 0, 0};
    float* __restrict__ outi = out + (size_t)img * NB32;
#pragma unroll
    for (int co = 0; co < 32; ++co) {
        float s = bsb[co];
#pragma unroll
        for (int ci = 0; ci < 32; ++ci) s += wsw[co * 32 + ci] * xv[ci];
        outi[co * NVOX + v] = s;
        const int g = co >> 3;
        gsum[g] += s;
        gsq[g]  += s * s;
    }
    __shared__ float red[4][8];
    const int lane = t & 63, wid = t >> 6;
#pragma unroll
    for (int g = 0; g < 4; ++g) {
        float s = gsum[g], q = gsq[g];
#pragma unroll
        for (int off = 32; off > 0; off >>= 1) {
            s += __shfl_down(s, off, 64);
            q += __shfl_down(q, off, 64);
        }
        if (lane == 0) { red[wid][2 * g] = s; red[wid][2 * g + 1] = q; }
    }
    __syncthreads();
    if (t < 8) {
        float s = red[0][t] + red[1][t] + red[2][t] + red[3][t];
        atomicAdd(&stats[img * 24 + 16 + t], s);
    }
}

// ---------------------------------------------------------------------------
// combine: GN2(conv2) + GN3(skip), residual add, lrelu, project to 16 emb ch
// ---------------------------------------------------------------------------
__global__ __launch_bounds__(256) void combine_kernel(
    const float* __restrict__ Bb, const float* __restrict__ Sk,
    const float* __restrict__ stats,
    const float* __restrict__ g2, const float* __restrict__ be2,
    const float* __restrict__ gs, const float* __restrict__ bes,
    const float* __restrict__ wp, const float* __restrict__ bp,
    float* __restrict__ emb)
{
    const int img = blockIdx.y;
    const int v   = blockIdx.x * 256 + threadIdx.x;
    const float Minv = 1.f / (8.f * (float)NVOX);
    float mu1[4], rs1[4], mu2[4], rs2[4];
#pragma unroll
    for (int g = 0; g < 4; ++g) {
        float s = stats[img * 24 + 8 + 2 * g], q = stats[img * 24 + 8 + 2 * g + 1];
        mu1[g] = s * Minv; rs1[g] = rsqrtf(q * Minv - mu1[g] * mu1[g] + 1e-5f);
        s = stats[img * 24 + 16 + 2 * g]; q = stats[img * 24 + 16 + 2 * g + 1];
        mu2[g] = s * Minv; rs2[g] = rsqrtf(q * Minv - mu2[g] * mu2[g] + 1e-5f);
    }
    float o[32];
#pragma unroll
    for (int c = 0; c < 32; ++c) {
        const int g = c >> 3;
        const float hv = (Bb[(size_t)img * NB32 + c * NVOX + v] - mu1[g]) * rs1[g] * g2[c] + be2[c];
        const float sv = (Sk[(size_t)img * NB32 + c * NVOX + v] - mu2[g]) * rs2[g] * gs[c] + bes[c];
        const float tv = hv + sv;
        o[c] = tv >= 0.f ? tv : 0.2f * tv;
    }
#pragma unroll
    for (int e = 0; e < 16; ++e) {
        float s = bp[e];
#pragma unroll
        for (int c = 0; c < 32; ++c) s += wp[e * 32 + c] * o[c];
        emb[(size_t)img * 16 * NVOX + e * NVOX + v] = s;
    }
}

// ---------------------------------------------------------------------------
// attention: Q = emb[fixed], K gathered from emb[moving] with edge clamp,
// softmax over 27 neighbors, displacement = sum attn * offset
// output is fp32 (reference output dtype)
// ---------------------------------------------------------------------------
__global__ __launch_bounds__(256) void attn_kernel(
    const float* __restrict__ emb, float* __restrict__ out)
{
    const int v = blockIdx.x * 256 + threadIdx.x;
    const int h = v >> 12, w = (v >> 6) & 63, d = v & 63;
    const float* __restrict__ Q = emb;               // img0 = fixed
    const float* __restrict__ K = emb + 16 * NVOX;   // img1 = moving
    float q[16];
#pragma unroll
    for (int e = 0; e < 16; ++e) q[e] = Q[e * NVOX + v];
    float sc[27];
    float m = -1e30f;
#pragma unroll
    for (int ih = 0; ih < 3; ++ih)
#pragma unroll
    for (int iw = 0; iw < 3; ++iw)
#pragma unroll
    for (int id = 0; id < 3; ++id) {
        int hh = h + ih - 1; hh = hh < 0 ? 0 : (hh > 63 ? 63 : hh);
        int ww = w + iw - 1; ww = ww < 0 ? 0 : (ww > 63 ? 63 : ww);
        int dd = d + id - 1; dd = dd < 0 ? 0 : (dd > 63 ? 63 : dd);
        const int nv = (hh << 12) + (ww << 6) + dd;
        float s = 0.f;
#pragma unroll
        for (int e = 0; e < 16; ++e) s += q[e] * K[e * NVOX + nv];
        s *= 0.25f;   // / sqrt(16)
        sc[(ih * 3 + iw) * 3 + id] = s;
        m = fmaxf(m, s);
    }
    float den = 0.f;
#pragma unroll
    for (int p = 0; p < 27; ++p) { sc[p] = __expf(sc[p] - m); den += sc[p]; }
    const float inv = 1.f / den;
    float r0 = 0.f, r1 = 0.f, r2 = 0.f;
#pragma unroll
    for (int ih = 0; ih < 3; ++ih)
#pragma unroll
    for (int iw = 0; iw < 3; ++iw)
#pragma unroll
    for (int id = 0; id < 3; ++id) {
        const float a = sc[(ih * 3 + iw) * 3 + id] * inv;
        r0 += a * (float)(ih - 1);
        r1 += a * (float)(iw - 1);
        r2 += a * (float)(id - 1);
    }
    out[v]            = r0;
    out[NVOX + v]     = r1;
    out[2 * NVOX + v] = r2;
}

// ---------------------------------------------------------------------------
extern "C" void kernel_launch(void* const* d_in, const int* in_sizes, int n_in,
                              void* d_out, int out_size, void* d_ws, size_t ws_size,
                              hipStream_t stream)
{
    (void)in_sizes; (void)n_in; (void)out_size; (void)ws_size;
    const float* feat_moving = (const float*)d_in[0];
    const float* feat_fixed  = (const float*)d_in[1];
    const float* w1  = (const float*)d_in[2];
    const float* b1  = (const float*)d_in[3];
    const float* g1  = (const float*)d_in[4];
    const float* be1 = (const float*)d_in[5];
    const float* w2  = (const float*)d_in[6];
    const float* b2  = (const float*)d_in[7];
    const float* g2  = (const float*)d_in[8];
    const float* be2 = (const float*)d_in[9];
    const float* wsw = (const float*)d_in[10];
    const float* bs  = (const float*)d_in[11];
    const float* gs  = (const float*)d_in[12];
    const float* bes = (const float*)d_in[13];
    const float* wp  = (const float*)d_in[14];
    const float* bp  = (const float*)d_in[15];

    float* A     = (float*)d_ws;          // [2][32][NVOX], later reused for skip
    float* Bb    = A + 2 * (size_t)NB32;  // [2][32][NVOX]
    float* emb   = Bb + 2 * (size_t)NB32; // [2][16][NVOX] (img0 fixed, img1 moving)
    float* wT1   = emb + 2 * 16 * (size_t)NVOX;
    float* wT2   = wT1 + 27648;
    float* stats = wT2 + 27648;           // [2 img][3 layers][4 groups][sum,sumsq]

    prep_kernel<<<108, 256, 0, stream>>>(w1, w2, wT1, wT2, stats);
    conv3_kernel<<<dim3(512, 2), 256, 0, stream>>>(feat_fixed, feat_moving, wT1, b1, A, stats, 0);
    gn_lrelu_kernel<<<2048, 256, 0, stream>>>(A, stats, g1, be1);
    conv3_kernel<<<dim3(512, 2), 256, 0, stream>>>(A, A + NB32, wT2, b2, Bb, stats, 1);
    skip_kernel<<<dim3(1024, 2), 256, 0, stream>>>(feat_fixed, feat_moving, wsw, bs, A, stats);
    combine_kernel<<<dim3(1024, 2), 256, 0, stream>>>(Bb, A, stats, g2, be2, gs, bes, wp, bp, emb);
    attn_kernel<<<1024, 256, 0, stream>>>(emb, (float*)d_out);
}

// Round 3
// 1106.642 us; speedup vs baseline: 2.8957x; 2.8957x over previous
//
#include <hip/hip_runtime.h>
#include <hip/hip_bf16.h>

#define NVOX (64*64*64)      // 262144 = 2^18
#define NB32 (32*NVOX)       // 2^23 floats per image of 32-ch volume

typedef short s8v __attribute__((ext_vector_type(8)));   // 8 bf16 = 4 VGPR (MFMA A/B frag)
typedef float f4v __attribute__((ext_vector_type(4)));   // MFMA C/D frag

__device__ inline ushort bfb(float f) {
    __hip_bfloat16 h = __float2bfloat16(f);
    return *reinterpret_cast<ushort*>(&h);
}

// ---------------------------------------------------------------------------
// prep: conv weights [co][ci][tap] -> bf16 [tap][co][ci]; zero stats
// ---------------------------------------------------------------------------
__global__ __launch_bounds__(256) void prep_kernel(
    const float* __restrict__ w1, const float* __restrict__ w2,
    ushort* __restrict__ wB1, ushort* __restrict__ wB2, float* __restrict__ stats)
{
    if (blockIdx.x == 0 && threadIdx.x < 48) stats[threadIdx.x] = 0.f;
    int i = blockIdx.x * 256 + threadIdx.x;
    if (i < 32 * 32 * 27) {
        int co  = i / 864;            // 864 = 32*27
        int rem = i - co * 864;
        int ci  = rem / 27;
        int tap = rem - ci * 27;
        wB1[(tap * 32 + co) * 32 + ci] = bfb(w1[i]);
        wB2[(tap * 32 + co) * 32 + ci] = bfb(w2[i]);
    }
}

// ---------------------------------------------------------------------------
// 3x3x3 conv 32->32 via bf16 MFMA implicit GEMM, zero pad, +bias, +GN stats.
// Block: 256 thr (4 waves), output tile (TH=4,TW=4,TD=32) = 512 vox x 32 co.
// LDS: halo tile 6x6x34 vox x 32ci bf16, [vox][ci] (vox stride 64B).
// Wave wid owns h'=wid; 4 w' x 2 d-subtiles = 8 M-tiles; N = 2 tiles of 16 co.
// grid: (512 = 16bh x 16bw x 2bd, 2 images)
// ---------------------------------------------------------------------------
__global__ __launch_bounds__(256) void conv3_mfma_kernel(
    const float* __restrict__ in0, const float* __restrict__ in1,
    const ushort* __restrict__ wB, const float* __restrict__ bias,
    float* __restrict__ out, float* __restrict__ stats, int layer)
{
    __shared__ __align__(16) ushort tile[36 * 34 * 32];   // 78336 B
    __shared__ float red[4][8];

    const int img = blockIdx.y;
    const float* __restrict__ in = img ? in1 : in0;
    const int bx = blockIdx.x;
    const int bd = bx & 1, bw = (bx >> 1) & 15, bh = bx >> 5;
    const int t = threadIdx.x;

    // ---- stage halo tile: 36 (hh,ww) x 8 ci-quads x 34 d, ds_write_b64 ----
    const int gd0 = bd * 32 - 1;
    for (int u = t; u < 288; u += 256) {
        const int ciq = u & 7, hw = u >> 3;
        const int hh = (hw * 43) >> 8;          // /6 for hw<36
        const int ww = hw - hh * 6;
        const int gh = bh * 4 + hh - 1, gw = bw * 4 + ww - 1;
        const bool rowok = ((unsigned)gh < 64u) && ((unsigned)gw < 64u);
        const float* __restrict__ rp = in + (size_t)(ciq * 4) * NVOX + (gh << 12) + (gw << 6);
        ushort* dst = tile + hw * 34 * 32 + ciq * 4;
        for (int dd = 0; dd < 34; ++dd) {
            const int gd = gd0 + dd;
            const bool ok = rowok && ((unsigned)gd < 64u);
            ushort4 pk;
            pk.x = ok ? bfb(rp[gd])            : (ushort)0;
            pk.y = ok ? bfb(rp[NVOX + gd])     : (ushort)0;
            pk.z = ok ? bfb(rp[2 * NVOX + gd]) : (ushort)0;
            pk.w = ok ? bfb(rp[3 * NVOX + gd]) : (ushort)0;
            *reinterpret_cast<ushort4*>(dst + dd * 32) = pk;
        }
    }
    __syncthreads();

    // ---- MFMA main loop ----
    const int lane = t & 63, wid = t >> 6;
    const int m = lane & 15, kc = lane >> 4;

    int pre8[4][2];   // A-frag base (s8v units) per (w'=i, d-subtile dt)
#pragma unroll
    for (int i = 0; i < 4; ++i)
#pragma unroll
    for (int dt = 0; dt < 2; ++dt)
        pre8[i][dt] = ((wid * 6 + i) * 34 + dt * 16 + m) * 4 + kc;

    const int wlane = m * 4 + kc;   // B-frag lane offset (s8v units) within a tap
    const s8v* __restrict__ tv = reinterpret_cast<const s8v*>(tile);
    const s8v* __restrict__ wv = reinterpret_cast<const s8v*>(wB);

    f4v acc[4][2][2] = {};
#pragma unroll
    for (int tap = 0; tap < 27; ++tap) {
        const int dh = tap / 9, dw = (tap / 3) % 3, dd = tap % 3;
        const int toff = ((dh * 6 + dw) * 34 + dd) * 4;
        const s8v bf0 = wv[tap * 128 + wlane];        // co = m
        const s8v bf1 = wv[tap * 128 + 64 + wlane];   // co = m+16
#pragma unroll
        for (int i = 0; i < 4; ++i)
#pragma unroll
        for (int dt = 0; dt < 2; ++dt) {
            const s8v a = tv[pre8[i][dt] + toff];
            acc[i][dt][0] = __builtin_amdgcn_mfma_f32_16x16x32_bf16(a, bf0, acc[i][dt][0], 0, 0, 0);
            acc[i][dt][1] = __builtin_amdgcn_mfma_f32_16x16x32_bf16(a, bf1, acc[i][dt][1], 0, 0, 0);
        }
    }

    // ---- epilogue: +bias, float4 store (4 consecutive d per frag), GN stats ----
    float* __restrict__ outi = out + (size_t)img * NB32;
    const float b0 = bias[m], b1 = bias[m + 16];
    float* __restrict__ op0 = outi + (size_t)m * NVOX;           // co = m
    float* __restrict__ op1 = outi + (size_t)(m + 16) * NVOX;    // co = m+16
    const int vbase = ((bh * 4 + wid) << 12) + ((bw * 4) << 6) + bd * 32 + kc * 4;
    float gsum[2] = {0.f, 0.f}, gsq[2] = {0.f, 0.f};
#pragma unroll
    for (int i = 0; i < 4; ++i) {
#pragma unroll
        for (int dt = 0; dt < 2; ++dt) {
            const int v = vbase + (i << 6) + dt * 16;
#pragma unroll
            for (int nt = 0; nt < 2; ++nt) {
                const f4v a = acc[i][dt][nt];
                const float bb = nt ? b1 : b0;
                const float x0 = a[0] + bb, x1 = a[1] + bb, x2 = a[2] + bb, x3 = a[3] + bb;
                float4 st; st.x = x0; st.y = x1; st.z = x2; st.w = x3;
                *reinterpret_cast<float4*>((nt ? op1 : op0) + v) = st;
                gsum[nt] += x0 + x1 + x2 + x3;
                gsq[nt]  += x0 * x0 + x1 * x1 + x2 * x2 + x3 * x3;
            }
        }
    }

#pragma unroll
    for (int nt = 0; nt < 2; ++nt) {
        float s = gsum[nt], q = gsq[nt];
        s += __shfl_xor(s, 16, 64); q += __shfl_xor(q, 16, 64);
        s += __shfl_xor(s, 32, 64); q += __shfl_xor(q, 32, 64);
        s += __shfl_xor(s, 1, 64);  q += __shfl_xor(q, 1, 64);
        s += __shfl_xor(s, 2, 64);  q += __shfl_xor(q, 2, 64);
        s += __shfl_xor(s, 4, 64);  q += __shfl_xor(q, 4, 64);
        if (lane == 0) { const int g = nt * 2;     red[wid][g * 2] = s; red[wid][g * 2 + 1] = q; }
        if (lane == 8) { const int g = nt * 2 + 1; red[wid][g * 2] = s; red[wid][g * 2 + 1] = q; }
    }
    __syncthreads();
    if (t < 8) {
        atomicAdd(&stats[img * 24 + layer * 8 + t],
                  red[0][t] + red[1][t] + red[2][t] + red[3][t]);
    }
}

// ---------------------------------------------------------------------------
// GroupNorm apply + leaky relu, in place, layer 0 stats
// ---------------------------------------------------------------------------
__global__ __launch_bounds__(256) void gn_lrelu_kernel(
    float* __restrict__ A, const float* __restrict__ stats,
    const float* __restrict__ gamma, const float* __restrict__ beta)
{
    const float Minv = 1.f / (8.f * (float)NVOX);
    const int total4 = (2 * NB32) / 4;
    for (int i4 = blockIdx.x * blockDim.x + threadIdx.x; i4 < total4;
         i4 += gridDim.x * blockDim.x) {
        const int i   = i4 * 4;
        const int img = i >> 23;
        const int c   = (i >> 18) & 31;
        const int g   = c >> 3;
        const float sum = stats[img * 24 + 2 * g], sq = stats[img * 24 + 2 * g + 1];
        const float mu = sum * Minv;
        const float rs = rsqrtf(sq * Minv - mu * mu + 1e-5f);
        const float sc = rs * gamma[c];
        const float sh = beta[c] - mu * sc;
        float4 vv = *reinterpret_cast<float4*>(A + i);
        float o0 = vv.x * sc + sh, o1 = vv.y * sc + sh, o2 = vv.z * sc + sh, o3 = vv.w * sc + sh;
        vv.x = o0 >= 0.f ? o0 : 0.2f * o0;
        vv.y = o1 >= 0.f ? o1 : 0.2f * o1;
        vv.z = o2 >= 0.f ? o2 : 0.2f * o2;
        vv.w = o3 >= 0.f ? o3 : 0.2f * o3;
        *reinterpret_cast<float4*>(A + i) = vv;
    }
}

// ---------------------------------------------------------------------------
// 1x1 skip conv 32->32 + bias + stats (layer 2)
// ---------------------------------------------------------------------------
__global__ __launch_bounds__(256) void skip_kernel(
    const float* __restrict__ in0, const float* __restrict__ in1,
    const float* __restrict__ wsw, const float* __restrict__ bsb,
    float* __restrict__ out, float* __restrict__ stats)
{
    const int img = blockIdx.y;
    const float* __restrict__ x = img ? in1 : in0;
    const int t = threadIdx.x;
    const int v = blockIdx.x * 256 + t;
    float xv[32];
#pragma unroll
    for (int ci = 0; ci < 32; ++ci) xv[ci] = x[ci * NVOX + v];
    float gsum[4] = {0, 0, 0, 0}, gsq[4] = {0, 0, 0, 0};
    float* __restrict__ outi = out + (size_t)img * NB32;
#pragma unroll
    for (int co = 0; co < 32; ++co) {
        float s = bsb[co];
#pragma unroll
        for (int ci = 0; ci < 32; ++ci) s += wsw[co * 32 + ci] * xv[ci];
        outi[co * NVOX + v] = s;
        const int g = co >> 3;
        gsum[g] += s;
        gsq[g]  += s * s;
    }
    __shared__ float red[4][8];
    const int lane = t & 63, wid = t >> 6;
#pragma unroll
    for (int g = 0; g < 4; ++g) {
        float s = gsum[g], q = gsq[g];
#pragma unroll
        for (int off = 32; off > 0; off >>= 1) {
            s += __shfl_down(s, off, 64);
            q += __shfl_down(q, off, 64);
        }
        if (lane == 0) { red[wid][2 * g] = s; red[wid][2 * g + 1] = q; }
    }
    __syncthreads();
    if (t < 8) {
        float s = red[0][t] + red[1][t] + red[2][t] + red[3][t];
        atomicAdd(&stats[img * 24 + 16 + t], s);
    }
}

// ---------------------------------------------------------------------------
// combine: GN2(conv2) + GN3(skip), residual add, lrelu, project to 16 emb ch
// ---------------------------------------------------------------------------
__global__ __launch_bounds__(256) void combine_kernel(
    const float* __restrict__ Bb, const float* __restrict__ Sk,
    const float* __restrict__ stats,
    const float* __restrict__ g2, const float* __restrict__ be2,
    const float* __restrict__ gs, const float* __restrict__ bes,
    const float* __restrict__ wp, const float* __restrict__ bp,
    float* __restrict__ emb)
{
    const int img = blockIdx.y;
    const int v   = blockIdx.x * 256 + threadIdx.x;
    const float Minv = 1.f / (8.f * (float)NVOX);
    float mu1[4], rs1[4], mu2[4], rs2[4];
#pragma unroll
    for (int g = 0; g < 4; ++g) {
        float s = stats[img * 24 + 8 + 2 * g], q = stats[img * 24 + 8 + 2 * g + 1];
        mu1[g] = s * Minv; rs1[g] = rsqrtf(q * Minv - mu1[g] * mu1[g] + 1e-5f);
        s = stats[img * 24 + 16 + 2 * g]; q = stats[img * 24 + 16 + 2 * g + 1];
        mu2[g] = s * Minv; rs2[g] = rsqrtf(q * Minv - mu2[g] * mu2[g] + 1e-5f);
    }
    float o[32];
#pragma unroll
    for (int c = 0; c < 32; ++c) {
        const int g = c >> 3;
        const float hv = (Bb[(size_t)img * NB32 + c * NVOX + v] - mu1[g]) * rs1[g] * g2[c] + be2[c];
        const float sv = (Sk[(size_t)img * NB32 + c * NVOX + v] - mu2[g]) * rs2[g] * gs[c] + bes[c];
        const float tv = hv + sv;
        o[c] = tv >= 0.f ? tv : 0.2f * tv;
    }
#pragma unroll
    for (int e = 0; e < 16; ++e) {
        float s = bp[e];
#pragma unroll
        for (int c = 0; c < 32; ++c) s += wp[e * 32 + c] * o[c];
        emb[(size_t)img * 16 * NVOX + e * NVOX + v] = s;
    }
}

// ---------------------------------------------------------------------------
// attention: Q = emb[fixed], K gathered from emb[moving] with edge clamp,
// softmax over 27 neighbors, displacement = sum attn * offset (fp32 out)
// ---------------------------------------------------------------------------
__global__ __launch_bounds__(256) void attn_kernel(
    const float* __restrict__ emb, float* __restrict__ out)
{
    const int v = blockIdx.x * 256 + threadIdx.x;
    const int h = v >> 12, w = (v >> 6) & 63, d = v & 63;
    const float* __restrict__ Q = emb;               // img0 = fixed
    const float* __restrict__ K = emb + 16 * NVOX;   // img1 = moving
    float q[16];
#pragma unroll
    for (int e = 0; e < 16; ++e) q[e] = Q[e * NVOX + v];
    float sc[27];
    float m = -1e30f;
#pragma unroll
    for (int ih = 0; ih < 3; ++ih)
#pragma unroll
    for (int iw = 0; iw < 3; ++iw)
#pragma unroll
    for (int id = 0; id < 3; ++id) {
        int hh = h + ih - 1; hh = hh < 0 ? 0 : (hh > 63 ? 63 : hh);
        int ww = w + iw - 1; ww = ww < 0 ? 0 : (ww > 63 ? 63 : ww);
        int dd = d + id - 1; dd = dd < 0 ? 0 : (dd > 63 ? 63 : dd);
        const int nv = (hh << 12) + (ww << 6) + dd;
        float s = 0.f;
#pragma unroll
        for (int e = 0; e < 16; ++e) s += q[e] * K[e * NVOX + nv];
        s *= 0.25f;   // / sqrt(16)
        sc[(ih * 3 + iw) * 3 + id] = s;
        m = fmaxf(m, s);
    }
    float den = 0.f;
#pragma unroll
    for (int p = 0; p < 27; ++p) { sc[p] = __expf(sc[p] - m); den += sc[p]; }
    const float inv = 1.f / den;
    float r0 = 0.f, r1 = 0.f, r2 = 0.f;
#pragma unroll
    for (int ih = 0; ih < 3; ++ih)
#pragma unroll
    for (int iw = 0; iw < 3; ++iw)
#pragma unroll
    for (int id = 0; id < 3; ++id) {
        const float a = sc[(ih * 3 + iw) * 3 + id] * inv;
        r0 += a * (float)(ih - 1);
        r1 += a * (float)(iw - 1);
        r2 += a * (float)(id - 1);
    }
    out[v]            = r0;
    out[NVOX + v]     = r1;
    out[2 * NVOX + v] = r2;
}

// ---------------------------------------------------------------------------
extern "C" void kernel_launch(void* const* d_in, const int* in_sizes, int n_in,
                              void* d_out, int out_size, void* d_ws, size_t ws_size,
                              hipStream_t stream)
{
    (void)in_sizes; (void)n_in; (void)out_size; (void)ws_size;
    const float* feat_moving = (const float*)d_in[0];
    const float* feat_fixed  = (const float*)d_in[1];
    const float* w1  = (const float*)d_in[2];
    const float* b1  = (const float*)d_in[3];
    const float* g1  = (const float*)d_in[4];
    const float* be1 = (const float*)d_in[5];
    const float* w2  = (const float*)d_in[6];
    const float* b2  = (const float*)d_in[7];
    const float* g2  = (const float*)d_in[8];
    const float* be2 = (const float*)d_in[9];
    const float* wsw = (const float*)d_in[10];
    const float* bs  = (const float*)d_in[11];
    const float* gs  = (const float*)d_in[12];
    const float* bes = (const float*)d_in[13];
    const float* wp  = (const float*)d_in[14];
    const float* bp  = (const float*)d_in[15];

    float* A     = (float*)d_ws;          // [2][32][NVOX], reused for skip out
    float* Bb    = A + 2 * (size_t)NB32;  // [2][32][NVOX]
    float* emb   = Bb + 2 * (size_t)NB32; // [2][16][NVOX] (img0 fixed, img1 moving)
    float* stats = emb + 2 * 16 * (size_t)NVOX;   // 48 floats
    ushort* wB1  = (ushort*)(stats + 64);
    ushort* wB2  = wB1 + 27648;

    prep_kernel<<<108, 256, 0, stream>>>(w1, w2, wB1, wB2, stats);
    conv3_mfma_kernel<<<dim3(512, 2), 256, 0, stream>>>(feat_fixed, feat_moving, wB1, b1, A, stats, 0);
    gn_lrelu_kernel<<<2048, 256, 0, stream>>>(A, stats, g1, be1);
    conv3_mfma_kernel<<<dim3(512, 2), 256, 0, stream>>>(A, A + NB32, wB2, b2, Bb, stats, 1);
    skip_kernel<<<dim3(1024, 2), 256, 0, stream>>>(feat_fixed, feat_moving, wsw, bs, A, stats);
    combine_kernel<<<dim3(1024, 2), 256, 0, stream>>>(Bb, A, stats, g2, be2, gs, bes, wp, bp, emb);
    attn_kernel<<<1024, 256, 0, stream>>>(emb, (float*)d_out);
}

// Round 4
// 286.883 us; speedup vs baseline: 11.1701x; 3.8575x over previous
//
#include <hip/hip_runtime.h>
#include <hip/hip_bf16.h>

#define NVOX (64*64*64)      // 262144 = 2^18
#define NB32 (32*NVOX)       // 2^23 floats per image of 32-ch volume

typedef short s8v __attribute__((ext_vector_type(8)));   // 8 bf16 = 4 VGPR (MFMA A/B frag)
typedef float f4v __attribute__((ext_vector_type(4)));   // MFMA C/D frag

__device__ inline ushort bfb(float f) {
    __hip_bfloat16 h = __float2bfloat16(f);
    return *reinterpret_cast<ushort*>(&h);
}

// ---------------------------------------------------------------------------
// prep: conv weights [co][ci][tap] -> bf16 [tap][co][ci]; zero stats
// ---------------------------------------------------------------------------
__global__ __launch_bounds__(256) void prep_kernel(
    const float* __restrict__ w1, const float* __restrict__ w2,
    ushort* __restrict__ wB1, ushort* __restrict__ wB2, float* __restrict__ stats)
{
    if (blockIdx.x == 0 && threadIdx.x < 48) stats[threadIdx.x] = 0.f;
    int i = blockIdx.x * 256 + threadIdx.x;
    if (i < 32 * 32 * 27) {
        int co  = i / 864;            // 864 = 32*27
        int rem = i - co * 864;
        int ci  = rem / 27;
        int tap = rem - ci * 27;
        wB1[(tap * 32 + co) * 32 + ci] = bfb(w1[i]);
        wB2[(tap * 32 + co) * 32 + ci] = bfb(w2[i]);
    }
}

// ---------------------------------------------------------------------------
// feat fp32 [c][vox] -> bf16 [vox][ci]  (per image)
// ---------------------------------------------------------------------------
__global__ __launch_bounds__(256) void tobf_kernel(
    const float* __restrict__ in0, const float* __restrict__ in1,
    ushort* __restrict__ outB)
{
    const int img = blockIdx.y;
    const float* __restrict__ in = img ? in1 : in0;
    ushort* __restrict__ op = outB + (size_t)img * NVOX * 32;
    const int v = blockIdx.x * 256 + threadIdx.x;
#pragma unroll
    for (int ciq = 0; ciq < 4; ++ciq) {
        s8v pk;
#pragma unroll
        for (int j = 0; j < 8; ++j)
            pk[j] = (short)bfb(in[(ciq * 8 + j) * NVOX + v]);
        *reinterpret_cast<s8v*>(op + (size_t)v * 32 + ciq * 8) = pk;
    }
}

// ---------------------------------------------------------------------------
// GN1 apply + lrelu: A fp32 [c][vox] -> bf16 [vox][ci]
// ---------------------------------------------------------------------------
__global__ __launch_bounds__(256) void gn_transpose_kernel(
    const float* __restrict__ A, const float* __restrict__ stats,
    const float* __restrict__ gamma, const float* __restrict__ beta,
    ushort* __restrict__ outB)
{
    const int img = blockIdx.y;
    const float* __restrict__ in = A + (size_t)img * NB32;
    ushort* __restrict__ op = outB + (size_t)img * NVOX * 32;
    const int v = blockIdx.x * 256 + threadIdx.x;
    const float Minv = 1.f / (8.f * (float)NVOX);
    float mu[4], rs[4];
#pragma unroll
    for (int g = 0; g < 4; ++g) {
        const float s = stats[img * 24 + 2 * g], q = stats[img * 24 + 2 * g + 1];
        mu[g] = s * Minv;
        rs[g] = rsqrtf(q * Minv - mu[g] * mu[g] + 1e-5f);
    }
#pragma unroll
    for (int ciq = 0; ciq < 4; ++ciq) {
        s8v pk;
#pragma unroll
        for (int j = 0; j < 8; ++j) {
            const int c = ciq * 8 + j;
            const int g = c >> 3;
            const float sc = rs[g] * gamma[c];
            const float sh = beta[c] - mu[g] * sc;
            float y = in[c * NVOX + v] * sc + sh;
            y = y >= 0.f ? y : 0.2f * y;
            pk[j] = (short)bfb(y);
        }
        *reinterpret_cast<s8v*>(op + (size_t)v * 32 + ciq * 8) = pk;
    }
}

// ---------------------------------------------------------------------------
// 3x3x3 conv 32->32 via bf16 MFMA implicit GEMM, zero pad, +bias, +GN stats.
// Input: bf16 [vox][ci]. Block: 4 waves, out tile (4h,4w,32d) x 32co.
// LDS halo tile [36 hw][34 d][32 ci] bf16; staging = contiguous 16B chunks.
// grid: (512 = 16bh x 16bw x 2bd, 2 images)
// ---------------------------------------------------------------------------
__global__ __launch_bounds__(256) void conv3_mfma_kernel(
    const ushort* __restrict__ inB,
    const ushort* __restrict__ wB, const float* __restrict__ bias,
    float* __restrict__ out, float* __restrict__ stats, int layer)
{
    __shared__ __align__(16) ushort tile[36 * 34 * 32];   // 78336 B
    __shared__ float red[4][8];

    const int img = blockIdx.y;
    const ushort* __restrict__ src = inB + (size_t)img * NVOX * 32;
    const int bx = blockIdx.x;
    const int bd = bx & 1, bw = (bx >> 1) & 15, bh = bx >> 5;
    const int t = threadIdx.x;

    // ---- stage halo tile: 36 rows x 34 d x 4 ci-quads of 16B ----
    const int gd0 = bd * 32 - 1, gh0 = bh * 4 - 1, gw0 = bw * 4 - 1;
    for (int u = t; u < 4896; u += 256) {       // 36*136
        const int r   = u / 136;
        const int rem = u - r * 136;
        const int dd = rem >> 2, ciq = rem & 3;
        const int hh = r / 6, ww = r - hh * 6;
        const int gh = gh0 + hh, gw = gw0 + ww, gd = gd0 + dd;
        s8v val = {0, 0, 0, 0, 0, 0, 0, 0};
        if (((unsigned)gh < 64u) && ((unsigned)gw < 64u) && ((unsigned)gd < 64u))
            val = *reinterpret_cast<const s8v*>(
                src + (size_t)(((gh << 12) + (gw << 6) + gd) << 5) + (ciq << 3));
        *reinterpret_cast<s8v*>(tile + (r * 34 + dd) * 32 + (ciq << 3)) = val;
    }
    __syncthreads();

    // ---- MFMA main loop ----
    const int lane = t & 63, wid = t >> 6;
    const int m = lane & 15, kc = lane >> 4;

    int pre8[4][2];   // A-frag base (s8v units) per (w'=i, d-subtile dt)
#pragma unroll
    for (int i = 0; i < 4; ++i)
#pragma unroll
    for (int dt = 0; dt < 2; ++dt)
        pre8[i][dt] = ((wid * 6 + i) * 34 + dt * 16 + m) * 4 + kc;

    const int wlane = m * 4 + kc;   // B-frag s8v offset within a tap
    const s8v* __restrict__ tv = reinterpret_cast<const s8v*>(tile);
    const s8v* __restrict__ wv = reinterpret_cast<const s8v*>(wB);

    f4v acc[4][2][2] = {};
#pragma unroll
    for (int tap = 0; tap < 27; ++tap) {
        const int dh = tap / 9, dw = (tap / 3) % 3, dd = tap % 3;
        const int toff = ((dh * 6 + dw) * 34 + dd) * 4;
        const s8v bf0 = wv[tap * 128 + wlane];        // co = m
        const s8v bf1 = wv[tap * 128 + 64 + wlane];   // co = m+16
#pragma unroll
        for (int i = 0; i < 4; ++i)
#pragma unroll
        for (int dt = 0; dt < 2; ++dt) {
            const s8v a = tv[pre8[i][dt] + toff];
            acc[i][dt][0] = __builtin_amdgcn_mfma_f32_16x16x32_bf16(a, bf0, acc[i][dt][0], 0, 0, 0);
            acc[i][dt][1] = __builtin_amdgcn_mfma_f32_16x16x32_bf16(a, bf1, acc[i][dt][1], 0, 0, 0);
        }
    }

    // ---- epilogue: +bias, float4 store along d, GN stats ----
    float* __restrict__ outi = out + (size_t)img * NB32;
    const float b0 = bias[m], b1 = bias[m + 16];
    float* __restrict__ op0 = outi + (size_t)m * NVOX;           // co = m
    float* __restrict__ op1 = outi + (size_t)(m + 16) * NVOX;    // co = m+16
    const int vbase = ((bh * 4 + wid) << 12) + ((bw * 4) << 6) + bd * 32 + kc * 4;
    float gsum[2] = {0.f, 0.f}, gsq[2] = {0.f, 0.f};
#pragma unroll
    for (int i = 0; i < 4; ++i) {
#pragma unroll
        for (int dt = 0; dt < 2; ++dt) {
            const int v = vbase + (i << 6) + dt * 16;
#pragma unroll
            for (int nt = 0; nt < 2; ++nt) {
                const f4v a = acc[i][dt][nt];
                const float bb = nt ? b1 : b0;
                const float x0 = a[0] + bb, x1 = a[1] + bb, x2 = a[2] + bb, x3 = a[3] + bb;
                float4 st; st.x = x0; st.y = x1; st.z = x2; st.w = x3;
                *reinterpret_cast<float4*>((nt ? op1 : op0) + v) = st;
                gsum[nt] += x0 + x1 + x2 + x3;
                gsq[nt]  += x0 * x0 + x1 * x1 + x2 * x2 + x3 * x3;
            }
        }
    }

#pragma unroll
    for (int nt = 0; nt < 2; ++nt) {
        float s = gsum[nt], q = gsq[nt];
        s += __shfl_xor(s, 16, 64); q += __shfl_xor(q, 16, 64);
        s += __shfl_xor(s, 32, 64); q += __shfl_xor(q, 32, 64);
        s += __shfl_xor(s, 1, 64);  q += __shfl_xor(q, 1, 64);
        s += __shfl_xor(s, 2, 64);  q += __shfl_xor(q, 2, 64);
        s += __shfl_xor(s, 4, 64);  q += __shfl_xor(q, 4, 64);
        if (lane == 0) { const int g = nt * 2;     red[wid][g * 2] = s; red[wid][g * 2 + 1] = q; }
        if (lane == 8) { const int g = nt * 2 + 1; red[wid][g * 2] = s; red[wid][g * 2 + 1] = q; }
    }
    __syncthreads();
    if (t < 8) {
        atomicAdd(&stats[img * 24 + layer * 8 + t],
                  red[0][t] + red[1][t] + red[2][t] + red[3][t]);
    }
}

// ---------------------------------------------------------------------------
// 1x1 skip conv 32->32 + bias + stats (layer 2), fp32 in/out [c][vox]
// ---------------------------------------------------------------------------
__global__ __launch_bounds__(256) void skip_kernel(
    const float* __restrict__ in0, const float* __restrict__ in1,
    const float* __restrict__ wsw, const float* __restrict__ bsb,
    float* __restrict__ out, float* __restrict__ stats)
{
    const int img = blockIdx.y;
    const float* __restrict__ x = img ? in1 : in0;
    const int t = threadIdx.x;
    const int v = blockIdx.x * 256 + t;
    float xv[32];
#pragma unroll
    for (int ci = 0; ci < 32; ++ci) xv[ci] = x[ci * NVOX + v];
    float gsum[4] = {0, 0, 0, 0}, gsq[4] = {0, 0, 0, 0};
    float* __restrict__ outi = out + (size_t)img * NB32;
#pragma unroll
    for (int co = 0; co < 32; ++co) {
        float s = bsb[co];
#pragma unroll
        for (int ci = 0; ci < 32; ++ci) s += wsw[co * 32 + ci] * xv[ci];
        outi[co * NVOX + v] = s;
        const int g = co >> 3;
        gsum[g] += s;
        gsq[g]  += s * s;
    }
    __shared__ float red[4][8];
    const int lane = t & 63, wid = t >> 6;
#pragma unroll
    for (int g = 0; g < 4; ++g) {
        float s = gsum[g], q = gsq[g];
#pragma unroll
        for (int off = 32; off > 0; off >>= 1) {
            s += __shfl_down(s, off, 64);
            q += __shfl_down(q, off, 64);
        }
        if (lane == 0) { red[wid][2 * g] = s; red[wid][2 * g + 1] = q; }
    }
    __syncthreads();
    if (t < 8) {
        float s = red[0][t] + red[1][t] + red[2][t] + red[3][t];
        atomicAdd(&stats[img * 24 + 16 + t], s);
    }
}

// ---------------------------------------------------------------------------
// combine: GN2(conv2) + GN3(skip), residual add, lrelu, project to 16 emb ch
// ---------------------------------------------------------------------------
__global__ __launch_bounds__(256) void combine_kernel(
    const float* __restrict__ Bb, const float* __restrict__ Sk,
    const float* __restrict__ stats,
    const float* __restrict__ g2, const float* __restrict__ be2,
    const float* __restrict__ gs, const float* __restrict__ bes,
    const float* __restrict__ wp, const float* __restrict__ bp,
    float* __restrict__ emb)
{
    const int img = blockIdx.y;
    const int v   = blockIdx.x * 256 + threadIdx.x;
    const float Minv = 1.f / (8.f * (float)NVOX);
    float mu1[4], rs1[4], mu2[4], rs2[4];
#pragma unroll
    for (int g = 0; g < 4; ++g) {
        float s = stats[img * 24 + 8 + 2 * g], q = stats[img * 24 + 8 + 2 * g + 1];
        mu1[g] = s * Minv; rs1[g] = rsqrtf(q * Minv - mu1[g] * mu1[g] + 1e-5f);
        s = stats[img * 24 + 16 + 2 * g]; q = stats[img * 24 + 16 + 2 * g + 1];
        mu2[g] = s * Minv; rs2[g] = rsqrtf(q * Minv - mu2[g] * mu2[g] + 1e-5f);
    }
    float o[32];
#pragma unroll
    for (int c = 0; c < 32; ++c) {
        const int g = c >> 3;
        const float hv = (Bb[(size_t)img * NB32 + c * NVOX + v] - mu1[g]) * rs1[g] * g2[c] + be2[c];
        const float sv = (Sk[(size_t)img * NB32 + c * NVOX + v] - mu2[g]) * rs2[g] * gs[c] + bes[c];
        const float tv = hv + sv;
        o[c] = tv >= 0.f ? tv : 0.2f * tv;
    }
#pragma unroll
    for (int e = 0; e < 16; ++e) {
        float s = bp[e];
#pragma unroll
        for (int c = 0; c < 32; ++c) s += wp[e * 32 + c] * o[c];
        emb[(size_t)img * 16 * NVOX + e * NVOX + v] = s;
    }
}

// ---------------------------------------------------------------------------
// attention: Q = emb[fixed], K gathered from emb[moving] with edge clamp,
// softmax over 27 neighbors, displacement = sum attn * offset (fp32 out)
// ---------------------------------------------------------------------------
__global__ __launch_bounds__(256) void attn_kernel(
    const float* __restrict__ emb, float* __restrict__ out)
{
    const int v = blockIdx.x * 256 + threadIdx.x;
    const int h = v >> 12, w = (v >> 6) & 63, d = v & 63;
    const float* __restrict__ Q = emb;               // img0 = fixed
    const float* __restrict__ K = emb + 16 * NVOX;   // img1 = moving
    float q[16];
#pragma unroll
    for (int e = 0; e < 16; ++e) q[e] = Q[e * NVOX + v];
    float sc[27];
    float m = -1e30f;
#pragma unroll
    for (int ih = 0; ih < 3; ++ih)
#pragma unroll
    for (int iw = 0; iw < 3; ++iw)
#pragma unroll
    for (int id = 0; id < 3; ++id) {
        int hh = h + ih - 1; hh = hh < 0 ? 0 : (hh > 63 ? 63 : hh);
        int ww = w + iw - 1; ww = ww < 0 ? 0 : (ww > 63 ? 63 : ww);
        int dd = d + id - 1; dd = dd < 0 ? 0 : (dd > 63 ? 63 : dd);
        const int nv = (hh << 12) + (ww << 6) + dd;
        float s = 0.f;
#pragma unroll
        for (int e = 0; e < 16; ++e) s += q[e] * K[e * NVOX + nv];
        s *= 0.25f;   // / sqrt(16)
        sc[(ih * 3 + iw) * 3 + id] = s;
        m = fmaxf(m, s);
    }
    float den = 0.f;
#pragma unroll
    for (int p = 0; p < 27; ++p) { sc[p] = __expf(sc[p] - m); den += sc[p]; }
    const float inv = 1.f / den;
    float r0 = 0.f, r1 = 0.f, r2 = 0.f;
#pragma unroll
    for (int ih = 0; ih < 3; ++ih)
#pragma unroll
    for (int iw = 0; iw < 3; ++iw)
#pragma unroll
    for (int id = 0; id < 3; ++id) {
        const float a = sc[(ih * 3 + iw) * 3 + id] * inv;
        r0 += a * (float)(ih - 1);
        r1 += a * (float)(iw - 1);
        r2 += a * (float)(id - 1);
    }
    out[v]            = r0;
    out[NVOX + v]     = r1;
    out[2 * NVOX + v] = r2;
}

// ---------------------------------------------------------------------------
extern "C" void kernel_launch(void* const* d_in, const int* in_sizes, int n_in,
                              void* d_out, int out_size, void* d_ws, size_t ws_size,
                              hipStream_t stream)
{
    (void)in_sizes; (void)n_in; (void)out_size; (void)ws_size;
    const float* feat_moving = (const float*)d_in[0];
    const float* feat_fixed  = (const float*)d_in[1];
    const float* w1  = (const float*)d_in[2];
    const float* b1  = (const float*)d_in[3];
    const float* g1  = (const float*)d_in[4];
    const float* be1 = (const float*)d_in[5];
    const float* w2  = (const float*)d_in[6];
    const float* b2  = (const float*)d_in[7];
    const float* g2  = (const float*)d_in[8];
    const float* be2 = (const float*)d_in[9];
    const float* wsw = (const float*)d_in[10];
    const float* bs  = (const float*)d_in[11];
    const float* gs  = (const float*)d_in[12];
    const float* bes = (const float*)d_in[13];
    const float* wp  = (const float*)d_in[14];
    const float* bp  = (const float*)d_in[15];

    // workspace layout (aliasing by lifetime; total ~168 MB):
    //   A   : [2][32][NVOX] fp32 — conv1 out, later reused as skip out
    //   Bb  : [2][32][NVOX] fp32 — conv2 out; featB (bf16 feat) aliases it
    //          (featB dead before conv2 writes Bb)
    //   emb : [2][16][NVOX] fp32 — AB (bf16 GN1 out) aliases it
    //          (AB dead before combine writes emb)
    float* A     = (float*)d_ws;
    float* Bb    = A + 2 * (size_t)NB32;
    float* emb   = Bb + 2 * (size_t)NB32;
    float* stats = emb + 2 * 16 * (size_t)NVOX;   // 48 floats
    ushort* wB1  = (ushort*)(stats + 64);
    ushort* wB2  = wB1 + 27648;
    ushort* featB = (ushort*)Bb;
    ushort* AB    = (ushort*)emb;

    prep_kernel<<<108, 256, 0, stream>>>(w1, w2, wB1, wB2, stats);
    tobf_kernel<<<dim3(1024, 2), 256, 0, stream>>>(feat_fixed, feat_moving, featB);
    conv3_mfma_kernel<<<dim3(512, 2), 256, 0, stream>>>(featB, wB1, b1, A, stats, 0);
    gn_transpose_kernel<<<dim3(1024, 2), 256, 0, stream>>>(A, stats, g1, be1, AB);
    conv3_mfma_kernel<<<dim3(512, 2), 256, 0, stream>>>(AB, wB2, b2, Bb, stats, 1);
    skip_kernel<<<dim3(1024, 2), 256, 0, stream>>>(feat_fixed, feat_moving, wsw, bs, A, stats);
    combine_kernel<<<dim3(1024, 2), 256, 0, stream>>>(Bb, A, stats, g2, be2, gs, bes, wp, bp, emb);
    attn_kernel<<<1024, 256, 0, stream>>>(emb, (float*)d_out);
}

// Round 5
// 218.944 us; speedup vs baseline: 14.6362x; 1.3103x over previous
//
#include <hip/hip_runtime.h>
#include <hip/hip_bf16.h>

#define NVOX (64*64*64)      // 262144 = 2^18
#define NB32 (32*NVOX)       // 2^23 elements per image of 32-ch volume

typedef short s8v __attribute__((ext_vector_type(8)));   // 8 bf16 = 4 VGPR (MFMA A/B frag)
typedef float f4v __attribute__((ext_vector_type(4)));   // MFMA C/D frag

__device__ inline ushort bfb(float f) {
    __hip_bfloat16 h = __float2bfloat16(f);
    return *reinterpret_cast<ushort*>(&h);
}
__device__ inline float bf2f(ushort u) {
    unsigned x = (unsigned)u << 16;
    return __builtin_bit_cast(float, x);
}

// ---------------------------------------------------------------------------
// prep: conv weights [co][ci][tap] -> bf16 [tap][co][ci]; skip W -> bf16;
// zero stats
// ---------------------------------------------------------------------------
__global__ __launch_bounds__(256) void prep_kernel(
    const float* __restrict__ w1, const float* __restrict__ w2,
    const float* __restrict__ wsw,
    ushort* __restrict__ wB1, ushort* __restrict__ wB2,
    ushort* __restrict__ wsB, float* __restrict__ stats)
{
    if (blockIdx.x == 0 && threadIdx.x < 48) stats[threadIdx.x] = 0.f;
    int i = blockIdx.x * 256 + threadIdx.x;
    if (i < 1024) wsB[i] = bfb(wsw[i]);              // [co][ci]
    if (i < 32 * 32 * 27) {
        int co  = i / 864;            // 864 = 32*27
        int rem = i - co * 864;
        int ci  = rem / 27;
        int tap = rem - ci * 27;
        wB1[(tap * 32 + co) * 32 + ci] = bfb(w1[i]);
        wB2[(tap * 32 + co) * 32 + ci] = bfb(w2[i]);
    }
}

// ---------------------------------------------------------------------------
// feat fp32 [c][vox] -> bf16 [vox][ci]  (per image)
// ---------------------------------------------------------------------------
__global__ __launch_bounds__(256) void tobf_kernel(
    const float* __restrict__ in0, const float* __restrict__ in1,
    ushort* __restrict__ outB)
{
    const int img = blockIdx.y;
    const float* __restrict__ in = img ? in1 : in0;
    ushort* __restrict__ op = outB + (size_t)img * NVOX * 32;
    const int v = blockIdx.x * 256 + threadIdx.x;
#pragma unroll
    for (int ciq = 0; ciq < 4; ++ciq) {
        s8v pk;
#pragma unroll
        for (int j = 0; j < 8; ++j)
            pk[j] = (short)bfb(in[(ciq * 8 + j) * NVOX + v]);
        *reinterpret_cast<s8v*>(op + (size_t)v * 32 + ciq * 8) = pk;
    }
}

// ---------------------------------------------------------------------------
// GN1 apply + lrelu: cA bf16 [c][vox] -> bf16 [vox][ci]
// ---------------------------------------------------------------------------
__global__ __launch_bounds__(256) void gn_transpose_kernel(
    const ushort* __restrict__ cA, const float* __restrict__ stats,
    const float* __restrict__ gamma, const float* __restrict__ beta,
    ushort* __restrict__ outB)
{
    const int img = blockIdx.y;
    const ushort* __restrict__ in = cA + (size_t)img * NB32;
    ushort* __restrict__ op = outB + (size_t)img * NVOX * 32;
    const int v = blockIdx.x * 256 + threadIdx.x;
    const float Minv = 1.f / (8.f * (float)NVOX);
    float mu[4], rs[4];
#pragma unroll
    for (int g = 0; g < 4; ++g) {
        const float s = stats[img * 24 + 2 * g], q = stats[img * 24 + 2 * g + 1];
        mu[g] = s * Minv;
        rs[g] = rsqrtf(q * Minv - mu[g] * mu[g] + 1e-5f);
    }
#pragma unroll
    for (int ciq = 0; ciq < 4; ++ciq) {
        s8v pk;
#pragma unroll
        for (int j = 0; j < 8; ++j) {
            const int c = ciq * 8 + j;
            const int g = c >> 3;
            const float sc = rs[g] * gamma[c];
            const float sh = beta[c] - mu[g] * sc;
            float y = bf2f(in[c * NVOX + v]) * sc + sh;
            y = y >= 0.f ? y : 0.2f * y;
            pk[j] = (short)bfb(y);
        }
        *reinterpret_cast<s8v*>(op + (size_t)v * 32 + ciq * 8) = pk;
    }
}

// ---------------------------------------------------------------------------
// 3x3x3 conv 32->32 via bf16 MFMA implicit GEMM, zero pad, +bias, +GN stats.
// Input: bf16 [vox][ci]. Output: bf16 [co][vox]. Block: 4 waves.
// LDS: 4 ci-quad planes of padded stride 1226 s8v (36*34=1224 used) —
// reads contiguous in r (2 lanes/bank = free), writes spread all banks.
// grid: (512 = 16bh x 16bw x 2bd, 2 images)
// ---------------------------------------------------------------------------
__global__ __launch_bounds__(256) void conv3_mfma_kernel(
    const ushort* __restrict__ inB,
    const ushort* __restrict__ wB, const float* __restrict__ bias,
    ushort* __restrict__ outB, float* __restrict__ stats, int layer)
{
    __shared__ __align__(16) ushort tile[4 * 1226 * 8];   // 78464 B
    __shared__ float red[4][8];

    const int img = blockIdx.y;
    const ushort* __restrict__ src = inB + (size_t)img * NVOX * 32;
    const int bx = blockIdx.x;
    const int bd = bx & 1, bw = (bx >> 1) & 15, bh = bx >> 5;
    const int t = threadIdx.x;

    // ---- stage halo tile: r = hw*34+dd (1224 rows), 4 ci-quads of 16B ----
    const int gd0 = bd * 32 - 1, gh0 = bh * 4 - 1, gw0 = bw * 4 - 1;
    s8v* __restrict__ tvw = reinterpret_cast<s8v*>(tile);
    for (int u = t; u < 4896; u += 256) {       // 1224*4
        const int r   = u >> 2;
        const int ciq = u & 3;
        const int hw = r / 34, dd = r - hw * 34;
        const int hh = hw / 6, ww = hw - hh * 6;
        const int gh = gh0 + hh, gw = gw0 + ww, gd = gd0 + dd;
        s8v val = {0, 0, 0, 0, 0, 0, 0, 0};
        if (((unsigned)gh < 64u) && ((unsigned)gw < 64u) && ((unsigned)gd < 64u))
            val = *reinterpret_cast<const s8v*>(
                src + (size_t)(((gh << 12) + (gw << 6) + gd) << 5) + (ciq << 3));
        tvw[ciq * 1226 + r] = val;
    }
    __syncthreads();

    // ---- MFMA main loop ----
    const int lane = t & 63, wid = t >> 6;
    const int m = lane & 15, kc = lane >> 4;

    int pre8[4][2];   // A-frag row base per (w'=i, d-subtile dt)
#pragma unroll
    for (int i = 0; i < 4; ++i)
#pragma unroll
    for (int dt = 0; dt < 2; ++dt)
        pre8[i][dt] = kc * 1226 + (wid * 6 + i) * 34 + dt * 16 + m;

    const int wlane = m * 4 + kc;   // B-frag s8v offset within a tap
    const s8v* __restrict__ tv = reinterpret_cast<const s8v*>(tile);
    const s8v* __restrict__ wv = reinterpret_cast<const s8v*>(wB);

    f4v acc[4][2][2] = {};
#pragma unroll
    for (int tap = 0; tap < 27; ++tap) {
        const int dh = tap / 9, dw = (tap / 3) % 3, dd = tap % 3;
        const int toff = (dh * 6 + dw) * 34 + dd;
        const s8v bf0 = wv[tap * 128 + wlane];        // co = m
        const s8v bf1 = wv[tap * 128 + 64 + wlane];   // co = m+16
#pragma unroll
        for (int i = 0; i < 4; ++i)
#pragma unroll
        for (int dt = 0; dt < 2; ++dt) {
            const s8v a = tv[pre8[i][dt] + toff];
            acc[i][dt][0] = __builtin_amdgcn_mfma_f32_16x16x32_bf16(a, bf0, acc[i][dt][0], 0, 0, 0);
            acc[i][dt][1] = __builtin_amdgcn_mfma_f32_16x16x32_bf16(a, bf1, acc[i][dt][1], 0, 0, 0);
        }
    }

    // ---- epilogue: +bias, bf16 ushort4 store along d, GN stats (fp32) ----
    ushort* __restrict__ outi = outB + (size_t)img * NB32;
    const float b0 = bias[m], b1 = bias[m + 16];
    ushort* __restrict__ op0 = outi + (size_t)m * NVOX;           // co = m
    ushort* __restrict__ op1 = outi + (size_t)(m + 16) * NVOX;    // co = m+16
    const int vbase = ((bh * 4 + wid) << 12) + ((bw * 4) << 6) + bd * 32 + kc * 4;
    float gsum[2] = {0.f, 0.f}, gsq[2] = {0.f, 0.f};
#pragma unroll
    for (int i = 0; i < 4; ++i) {
#pragma unroll
        for (int dt = 0; dt < 2; ++dt) {
            const int v = vbase + (i << 6) + dt * 16;
#pragma unroll
            for (int nt = 0; nt < 2; ++nt) {
                const f4v a = acc[i][dt][nt];
                const float bb = nt ? b1 : b0;
                const float x0 = a[0] + bb, x1 = a[1] + bb, x2 = a[2] + bb, x3 = a[3] + bb;
                ushort4 pk;
                pk.x = bfb(x0); pk.y = bfb(x1); pk.z = bfb(x2); pk.w = bfb(x3);
                *reinterpret_cast<ushort4*>((nt ? op1 : op0) + v) = pk;
                gsum[nt] += x0 + x1 + x2 + x3;
                gsq[nt]  += x0 * x0 + x1 * x1 + x2 * x2 + x3 * x3;
            }
        }
    }

#pragma unroll
    for (int nt = 0; nt < 2; ++nt) {
        float s = gsum[nt], q = gsq[nt];
        s += __shfl_xor(s, 16, 64); q += __shfl_xor(q, 16, 64);
        s += __shfl_xor(s, 32, 64); q += __shfl_xor(q, 32, 64);
        s += __shfl_xor(s, 1, 64);  q += __shfl_xor(q, 1, 64);
        s += __shfl_xor(s, 2, 64);  q += __shfl_xor(q, 2, 64);
        s += __shfl_xor(s, 4, 64);  q += __shfl_xor(q, 4, 64);
        if (lane == 0) { const int g = nt * 2;     red[wid][g * 2] = s; red[wid][g * 2 + 1] = q; }
        if (lane == 8) { const int g = nt * 2 + 1; red[wid][g * 2] = s; red[wid][g * 2 + 1] = q; }
    }
    __syncthreads();
    if (t < 8) {
        atomicAdd(&stats[img * 24 + layer * 8 + t],
                  red[0][t] + red[1][t] + red[2][t] + red[3][t]);
    }
}

// ---------------------------------------------------------------------------
// 1x1 skip conv via MFMA: featB bf16 [vox][ci] -> skipB bf16 [co][vox]
// + bias + GN stats (layer 2). Wave handles 64 voxels; M=32co, K=32ci.
// ---------------------------------------------------------------------------
__global__ __launch_bounds__(256) void skip_mfma_kernel(
    const ushort* __restrict__ featB, const ushort* __restrict__ wsB,
    const float* __restrict__ bsb,
    ushort* __restrict__ skipB, float* __restrict__ stats)
{
    __shared__ float red[4][8];
    const int img = blockIdx.y;
    const s8v* __restrict__ fv =
        reinterpret_cast<const s8v*>(featB + (size_t)img * NVOX * 32);
    ushort* __restrict__ dst = skipB + (size_t)img * NB32;
    const int t = threadIdx.x, lane = t & 63, wid = t >> 6;
    const int m = lane & 15, kc = lane >> 4;
    const int vb = blockIdx.x * 256 + wid * 64;
    const s8v* __restrict__ wv = reinterpret_cast<const s8v*>(wsB);
    const s8v a0 = wv[m * 4 + kc];          // A rows co 0..15
    const s8v a1 = wv[(m + 16) * 4 + kc];   // A rows co 16..31

    f4v acc[2][4] = {};
#pragma unroll
    for (int nt = 0; nt < 4; ++nt) {
        const s8v b = fv[(vb + nt * 16 + m) * 4 + kc];
        acc[0][nt] = __builtin_amdgcn_mfma_f32_16x16x32_bf16(a0, b, acc[0][nt], 0, 0, 0);
        acc[1][nt] = __builtin_amdgcn_mfma_f32_16x16x32_bf16(a1, b, acc[1][nt], 0, 0, 0);
    }

    // D: col = lane&15 = vox offset, row = kc*4+j = co (within 16) + 16*mt
    float s0 = 0.f, q0 = 0.f, s1 = 0.f, q1 = 0.f;
#pragma unroll
    for (int mt = 0; mt < 2; ++mt) {
#pragma unroll
        for (int nt = 0; nt < 4; ++nt) {
            const f4v a = acc[mt][nt];
#pragma unroll
            for (int j = 0; j < 4; ++j) {
                const int co = mt * 16 + kc * 4 + j;
                const float x = a[j] + bsb[co];
                dst[(size_t)co * NVOX + vb + nt * 16 + m] = bfb(x);
                if (mt == 0) { s0 += x; q0 += x * x; }
                else         { s1 += x; q1 += x * x; }
            }
        }
    }
    // reduce over vox lanes (m bits) then kc pairs (xor 16)
    float v4[4] = {s0, q0, s1, q1};
#pragma unroll
    for (int k = 0; k < 4; ++k) {
        float x = v4[k];
        x += __shfl_xor(x, 1, 64);
        x += __shfl_xor(x, 2, 64);
        x += __shfl_xor(x, 4, 64);
        x += __shfl_xor(x, 8, 64);
        x += __shfl_xor(x, 16, 64);
        v4[k] = x;
    }
    // lane 0 (kc=0): groups 0 (mt0), 2 (mt1); lane 32 (kc=2): groups 1, 3
    if (lane == 0)  { red[wid][0] = v4[0]; red[wid][1] = v4[1]; red[wid][4] = v4[2]; red[wid][5] = v4[3]; }
    if (lane == 32) { red[wid][2] = v4[0]; red[wid][3] = v4[1]; red[wid][6] = v4[2]; red[wid][7] = v4[3]; }
    __syncthreads();
    if (t < 8) {
        atomicAdd(&stats[img * 24 + 16 + t],
                  red[0][t] + red[1][t] + red[2][t] + red[3][t]);
    }
}

// ---------------------------------------------------------------------------
// combine: GN2(cB) + GN3(skipB), residual add, lrelu, project to 16 emb ch
// inputs bf16 [co][vox]; emb fp32 [e][vox]
// ---------------------------------------------------------------------------
__global__ __launch_bounds__(256) void combine_kernel(
    const ushort* __restrict__ Bb, const ushort* __restrict__ Sk,
    const float* __restrict__ stats,
    const float* __restrict__ g2, const float* __restrict__ be2,
    const float* __restrict__ gs, const float* __restrict__ bes,
    const float* __restrict__ wp, const float* __restrict__ bp,
    float* __restrict__ emb)
{
    const int img = blockIdx.y;
    const int v   = blockIdx.x * 256 + threadIdx.x;
    const float Minv = 1.f / (8.f * (float)NVOX);
    float mu1[4], rs1[4], mu2[4], rs2[4];
#pragma unroll
    for (int g = 0; g < 4; ++g) {
        float s = stats[img * 24 + 8 + 2 * g], q = stats[img * 24 + 8 + 2 * g + 1];
        mu1[g] = s * Minv; rs1[g] = rsqrtf(q * Minv - mu1[g] * mu1[g] + 1e-5f);
        s = stats[img * 24 + 16 + 2 * g]; q = stats[img * 24 + 16 + 2 * g + 1];
        mu2[g] = s * Minv; rs2[g] = rsqrtf(q * Minv - mu2[g] * mu2[g] + 1e-5f);
    }
    const ushort* __restrict__ bb = Bb + (size_t)img * NB32;
    const ushort* __restrict__ sk = Sk + (size_t)img * NB32;
    float o[32];
#pragma unroll
    for (int c = 0; c < 32; ++c) {
        const int g = c >> 3;
        const float hv = (bf2f(bb[c * NVOX + v]) - mu1[g]) * rs1[g] * g2[c] + be2[c];
        const float sv = (bf2f(sk[c * NVOX + v]) - mu2[g]) * rs2[g] * gs[c] + bes[c];
        const float tv = hv + sv;
        o[c] = tv >= 0.f ? tv : 0.2f * tv;
    }
#pragma unroll
    for (int e = 0; e < 16; ++e) {
        float s = bp[e];
#pragma unroll
        for (int c = 0; c < 32; ++c) s += wp[e * 32 + c] * o[c];
        emb[(size_t)img * 16 * NVOX + e * NVOX + v] = s;
    }
}

// ---------------------------------------------------------------------------
// attention: Q = emb[fixed], K gathered from emb[moving] with edge clamp,
// softmax over 27 neighbors, displacement = sum attn * offset (fp32 out)
// ---------------------------------------------------------------------------
__global__ __launch_bounds__(256) void attn_kernel(
    const float* __restrict__ emb, float* __restrict__ out)
{
    const int v = blockIdx.x * 256 + threadIdx.x;
    const int h = v >> 12, w = (v >> 6) & 63, d = v & 63;
    const float* __restrict__ Q = emb;               // img0 = fixed
    const float* __restrict__ K = emb + 16 * NVOX;   // img1 = moving
    float q[16];
#pragma unroll
    for (int e = 0; e < 16; ++e) q[e] = Q[e * NVOX + v];
    float sc[27];
    float m = -1e30f;
#pragma unroll
    for (int ih = 0; ih < 3; ++ih)
#pragma unroll
    for (int iw = 0; iw < 3; ++iw)
#pragma unroll
    for (int id = 0; id < 3; ++id) {
        int hh = h + ih - 1; hh = hh < 0 ? 0 : (hh > 63 ? 63 : hh);
        int ww = w + iw - 1; ww = ww < 0 ? 0 : (ww > 63 ? 63 : ww);
        int dd = d + id - 1; dd = dd < 0 ? 0 : (dd > 63 ? 63 : dd);
        const int nv = (hh << 12) + (ww << 6) + dd;
        float s = 0.f;
#pragma unroll
        for (int e = 0; e < 16; ++e) s += q[e] * K[e * NVOX + nv];
        s *= 0.25f;   // / sqrt(16)
        sc[(ih * 3 + iw) * 3 + id] = s;
        m = fmaxf(m, s);
    }
    float den = 0.f;
#pragma unroll
    for (int p = 0; p < 27; ++p) { sc[p] = __expf(sc[p] - m); den += sc[p]; }
    const float inv = 1.f / den;
    float r0 = 0.f, r1 = 0.f, r2 = 0.f;
#pragma unroll
    for (int ih = 0; ih < 3; ++ih)
#pragma unroll
    for (int iw = 0; iw < 3; ++iw)
#pragma unroll
    for (int id = 0; id < 3; ++id) {
        const float a = sc[(ih * 3 + iw) * 3 + id] * inv;
        r0 += a * (float)(ih - 1);
        r1 += a * (float)(iw - 1);
        r2 += a * (float)(id - 1);
    }
    out[v]            = r0;
    out[NVOX + v]     = r1;
    out[2 * NVOX + v] = r2;
}

// ---------------------------------------------------------------------------
extern "C" void kernel_launch(void* const* d_in, const int* in_sizes, int n_in,
                              void* d_out, int out_size, void* d_ws, size_t ws_size,
                              hipStream_t stream)
{
    (void)in_sizes; (void)n_in; (void)out_size; (void)ws_size;
    const float* feat_moving = (const float*)d_in[0];
    const float* feat_fixed  = (const float*)d_in[1];
    const float* w1  = (const float*)d_in[2];
    const float* b1  = (const float*)d_in[3];
    const float* g1  = (const float*)d_in[4];
    const float* be1 = (const float*)d_in[5];
    const float* w2  = (const float*)d_in[6];
    const float* b2  = (const float*)d_in[7];
    const float* g2  = (const float*)d_in[8];
    const float* be2 = (const float*)d_in[9];
    const float* wsw = (const float*)d_in[10];
    const float* bs  = (const float*)d_in[11];
    const float* gs  = (const float*)d_in[12];
    const float* bes = (const float*)d_in[13];
    const float* wp  = (const float*)d_in[14];
    const float* bp  = (const float*)d_in[15];

    // workspace layout by lifetime (MiB offsets), max ~160.1 MiB:
    //   featB [0,32)   bf16 [vox][ci]   live tobf..skip
    //   cA    [32,64)  bf16 [co][vox]   live conv1..gn_t ; emb aliases after
    //   AB    [64,96)  bf16 [vox][ci]   live gn_t..conv2
    //   cB    [96,128) bf16 [co][vox]   live conv2..combine
    //   skipB [128,160)bf16 [co][vox]   live skip..combine
    //   emb = cA region, fp32 [e][vox] (exactly 32 MiB), live combine..attn
    char* base = (char*)d_ws;
    ushort* featB = (ushort*)base;
    ushort* cA    = (ushort*)(base + (32ull << 20));
    ushort* AB    = (ushort*)(base + (64ull << 20));
    ushort* cB    = (ushort*)(base + (96ull << 20));
    ushort* skipB = (ushort*)(base + (128ull << 20));
    float*  emb   = (float*)(base + (32ull << 20));
    float*  stats = (float*)(base + (160ull << 20));
    ushort* wB1   = (ushort*)(stats + 64);
    ushort* wB2   = wB1 + 27648;
    ushort* wsB   = wB2 + 27648;

    prep_kernel<<<108, 256, 0, stream>>>(w1, w2, wsw, wB1, wB2, wsB, stats);
    tobf_kernel<<<dim3(1024, 2), 256, 0, stream>>>(feat_fixed, feat_moving, featB);
    conv3_mfma_kernel<<<dim3(512, 2), 256, 0, stream>>>(featB, wB1, b1, cA, stats, 0);
    gn_transpose_kernel<<<dim3(1024, 2), 256, 0, stream>>>(cA, stats, g1, be1, AB);
    conv3_mfma_kernel<<<dim3(512, 2), 256, 0, stream>>>(AB, wB2, b2, cB, stats, 1);
    skip_mfma_kernel<<<dim3(1024, 2), 256, 0, stream>>>(featB, wsB, bs, skipB, stats);
    combine_kernel<<<dim3(1024, 2), 256, 0, stream>>>(cB, skipB, stats, g2, be2, gs, bes, wp, bp, emb);
    attn_kernel<<<1024, 256, 0, stream>>>(emb, (float*)d_out);
}

// Round 6
// 217.013 us; speedup vs baseline: 14.7664x; 1.0089x over previous
//
#include <hip/hip_runtime.h>
#include <hip/hip_bf16.h>

#define NVOX (64*64*64)      // 262144 = 2^18
#define NB32 (32*NVOX)       // 2^23 elements per image of 32-ch volume

typedef short s8v __attribute__((ext_vector_type(8)));   // 8 bf16 = 4 VGPR (MFMA A/B frag)
typedef float f4v __attribute__((ext_vector_type(4)));   // MFMA C/D frag

__device__ inline ushort bfb(float f) {
    __hip_bfloat16 h = __float2bfloat16(f);
    return *reinterpret_cast<ushort*>(&h);
}
__device__ inline float bf2f(ushort u) {
    unsigned x = (unsigned)u << 16;
    return __builtin_bit_cast(float, x);
}

// ---------------------------------------------------------------------------
// prep: conv weights [co][ci][tap] -> bf16 [tap][co][ci]; zero stats
// ---------------------------------------------------------------------------
__global__ __launch_bounds__(256) void prep_kernel(
    const float* __restrict__ w1, const float* __restrict__ w2,
    ushort* __restrict__ wB1, ushort* __restrict__ wB2, float* __restrict__ stats)
{
    if (blockIdx.x == 0 && threadIdx.x < 48) stats[threadIdx.x] = 0.f;
    int i = blockIdx.x * 256 + threadIdx.x;
    if (i < 32 * 32 * 27) {
        int co  = i / 864;            // 864 = 32*27
        int rem = i - co * 864;
        int ci  = rem / 27;
        int tap = rem - ci * 27;
        wB1[(tap * 32 + co) * 32 + ci] = bfb(w1[i]);
        wB2[(tap * 32 + co) * 32 + ci] = bfb(w2[i]);
    }
}

// ---------------------------------------------------------------------------
// fused: feat fp32 [c][vox] -> featB bf16 [vox][ci]
//        + skip 1x1 conv (fp32 VALU) -> skipB bf16 [vox][co] + GN3 stats
// ---------------------------------------------------------------------------
__global__ __launch_bounds__(256) void tobf_skip_kernel(
    const float* __restrict__ in0, const float* __restrict__ in1,
    const float* __restrict__ wsw, const float* __restrict__ bsb,
    ushort* __restrict__ featB, ushort* __restrict__ skipB,
    float* __restrict__ stats)
{
    const int img = blockIdx.y;
    const float* __restrict__ in = img ? in1 : in0;
    const int t = threadIdx.x;
    const int v = blockIdx.x * 256 + t;

    float xv[32];
#pragma unroll
    for (int ciq = 0; ciq < 4; ++ciq) {
        s8v pk;
#pragma unroll
        for (int j = 0; j < 8; ++j) {
            xv[ciq * 8 + j] = in[(ciq * 8 + j) * NVOX + v];
            pk[j] = (short)bfb(xv[ciq * 8 + j]);
        }
        *reinterpret_cast<s8v*>(featB + ((size_t)img * NVOX + v) * 32 + ciq * 8) = pk;
    }

    float gsum[4] = {0, 0, 0, 0}, gsq[4] = {0, 0, 0, 0};
    ushort* __restrict__ sko = skipB + ((size_t)img * NVOX + v) * 32;
#pragma unroll
    for (int coq = 0; coq < 4; ++coq) {
        s8v pk;
#pragma unroll
        for (int j = 0; j < 8; ++j) {
            const int co = coq * 8 + j;
            float s = bsb[co];
#pragma unroll
            for (int ci = 0; ci < 32; ++ci) s += wsw[co * 32 + ci] * xv[ci];
            pk[j] = (short)bfb(s);
            const int g = co >> 3;
            gsum[g] += s;
            gsq[g]  += s * s;
        }
        *reinterpret_cast<s8v*>(sko + coq * 8) = pk;
    }

    __shared__ float red[4][8];
    const int lane = t & 63, wid = t >> 6;
#pragma unroll
    for (int g = 0; g < 4; ++g) {
        float s = gsum[g], q = gsq[g];
#pragma unroll
        for (int off = 32; off > 0; off >>= 1) {
            s += __shfl_down(s, off, 64);
            q += __shfl_down(q, off, 64);
        }
        if (lane == 0) { red[wid][2 * g] = s; red[wid][2 * g + 1] = q; }
    }
    __syncthreads();
    if (t < 8) {
        atomicAdd(&stats[img * 24 + 16 + t],
                  red[0][t] + red[1][t] + red[2][t] + red[3][t]);
    }
}

// ---------------------------------------------------------------------------
// GN1 apply + lrelu: cA bf16 [c][vox] -> bf16 [vox][ci]
// ---------------------------------------------------------------------------
__global__ __launch_bounds__(256) void gn_transpose_kernel(
    const ushort* __restrict__ cA, const float* __restrict__ stats,
    const float* __restrict__ gamma, const float* __restrict__ beta,
    ushort* __restrict__ outB)
{
    const int img = blockIdx.y;
    const ushort* __restrict__ in = cA + (size_t)img * NB32;
    ushort* __restrict__ op = outB + (size_t)img * NVOX * 32;
    const int v = blockIdx.x * 256 + threadIdx.x;
    const float Minv = 1.f / (8.f * (float)NVOX);
    float mu[4], rs[4];
#pragma unroll
    for (int g = 0; g < 4; ++g) {
        const float s = stats[img * 24 + 2 * g], q = stats[img * 24 + 2 * g + 1];
        mu[g] = s * Minv;
        rs[g] = rsqrtf(q * Minv - mu[g] * mu[g] + 1e-5f);
    }
#pragma unroll
    for (int ciq = 0; ciq < 4; ++ciq) {
        s8v pk;
#pragma unroll
        for (int j = 0; j < 8; ++j) {
            const int c = ciq * 8 + j;
            const int g = c >> 3;
            const float sc = rs[g] * gamma[c];
            const float sh = beta[c] - mu[g] * sc;
            float y = bf2f(in[c * NVOX + v]) * sc + sh;
            y = y >= 0.f ? y : 0.2f * y;
            pk[j] = (short)bfb(y);
        }
        *reinterpret_cast<s8v*>(op + (size_t)v * 32 + ciq * 8) = pk;
    }
}

// ---------------------------------------------------------------------------
// 3x3x3 conv 32->32 via bf16 MFMA implicit GEMM, zero pad, +bias, +GN stats.
// Input: bf16 [vox][ci]. Output: bf16 [co][vox]. Block: 512 thr (8 waves)
// for 16 waves/CU occupancy at 78.5KB LDS (2 blocks/CU).
// LDS: 4 ci-quad planes of padded stride 1226 s8v.
// Wave wid: h' = wid&3, w'-half = wid>>2 (2 w' each); 2 d-subtiles.
// grid: (512 = 16bh x 16bw x 2bd, 2 images)
// ---------------------------------------------------------------------------
__global__ __launch_bounds__(512) void conv3_mfma_kernel(
    const ushort* __restrict__ inB,
    const ushort* __restrict__ wB, const float* __restrict__ bias,
    ushort* __restrict__ outB, float* __restrict__ stats, int layer)
{
    __shared__ __align__(16) ushort tile[4 * 1226 * 8];   // 78464 B
    __shared__ float red[8][8];

    const int img = blockIdx.y;
    const ushort* __restrict__ src = inB + (size_t)img * NVOX * 32;
    const int bx = blockIdx.x;
    const int bd = bx & 1, bw = (bx >> 1) & 15, bh = bx >> 5;
    const int t = threadIdx.x;

    // ---- stage halo tile: r = hw*34+dd (1224 rows), 4 ci-quads of 16B ----
    const int gd0 = bd * 32 - 1, gh0 = bh * 4 - 1, gw0 = bw * 4 - 1;
    s8v* __restrict__ tvw = reinterpret_cast<s8v*>(tile);
    for (int u = t; u < 4896; u += 512) {       // 1224*4
        const int r   = u >> 2;
        const int ciq = u & 3;
        const int hw = r / 34, dd = r - hw * 34;
        const int hh = hw / 6, ww = hw - hh * 6;
        const int gh = gh0 + hh, gw = gw0 + ww, gd = gd0 + dd;
        s8v val = {0, 0, 0, 0, 0, 0, 0, 0};
        if (((unsigned)gh < 64u) && ((unsigned)gw < 64u) && ((unsigned)gd < 64u))
            val = *reinterpret_cast<const s8v*>(
                src + (size_t)(((gh << 12) + (gw << 6) + gd) << 5) + (ciq << 3));
        tvw[ciq * 1226 + r] = val;
    }
    __syncthreads();

    // ---- MFMA main loop ----
    const int lane = t & 63, wid = t >> 6;
    const int m = lane & 15, kc = lane >> 4;
    const int hp = wid & 3, wh = wid >> 2;

    int pre8[2][2];   // A-frag row base per (w' = wh*2+i2, d-subtile dt)
#pragma unroll
    for (int i2 = 0; i2 < 2; ++i2)
#pragma unroll
    for (int dt = 0; dt < 2; ++dt)
        pre8[i2][dt] = kc * 1226 + (hp * 6 + wh * 2 + i2) * 34 + dt * 16 + m;

    const int wlane = m * 4 + kc;   // B-frag s8v offset within a tap
    const s8v* __restrict__ tv = reinterpret_cast<const s8v*>(tile);
    const s8v* __restrict__ wv = reinterpret_cast<const s8v*>(wB);

    f4v acc[2][2][2] = {};
#pragma unroll
    for (int tap = 0; tap < 27; ++tap) {
        const int dh = tap / 9, dw = (tap / 3) % 3, dd = tap % 3;
        const int toff = (dh * 6 + dw) * 34 + dd;
        const s8v bf0 = wv[tap * 128 + wlane];        // co = m
        const s8v bf1 = wv[tap * 128 + 64 + wlane];   // co = m+16
#pragma unroll
        for (int i2 = 0; i2 < 2; ++i2)
#pragma unroll
        for (int dt = 0; dt < 2; ++dt) {
            const s8v a = tv[pre8[i2][dt] + toff];
            acc[i2][dt][0] = __builtin_amdgcn_mfma_f32_16x16x32_bf16(a, bf0, acc[i2][dt][0], 0, 0, 0);
            acc[i2][dt][1] = __builtin_amdgcn_mfma_f32_16x16x32_bf16(a, bf1, acc[i2][dt][1], 0, 0, 0);
        }
    }

    // ---- epilogue: +bias, bf16 ushort4 store along d, GN stats (fp32) ----
    ushort* __restrict__ outi = outB + (size_t)img * NB32;
    const float b0 = bias[m], b1 = bias[m + 16];
    ushort* __restrict__ op0 = outi + (size_t)m * NVOX;           // co = m
    ushort* __restrict__ op1 = outi + (size_t)(m + 16) * NVOX;    // co = m+16
    float gsum[2] = {0.f, 0.f}, gsq[2] = {0.f, 0.f};
#pragma unroll
    for (int i2 = 0; i2 < 2; ++i2) {
#pragma unroll
        for (int dt = 0; dt < 2; ++dt) {
            const int v = ((bh * 4 + hp) << 12) + ((bw * 4 + wh * 2 + i2) << 6)
                        + bd * 32 + dt * 16 + kc * 4;
#pragma unroll
            for (int nt = 0; nt < 2; ++nt) {
                const f4v a = acc[i2][dt][nt];
                const float bb = nt ? b1 : b0;
                const float x0 = a[0] + bb, x1 = a[1] + bb, x2 = a[2] + bb, x3 = a[3] + bb;
                ushort4 pk;
                pk.x = bfb(x0); pk.y = bfb(x1); pk.z = bfb(x2); pk.w = bfb(x3);
                *reinterpret_cast<ushort4*>((nt ? op1 : op0) + v) = pk;
                gsum[nt] += x0 + x1 + x2 + x3;
                gsq[nt]  += x0 * x0 + x1 * x1 + x2 * x2 + x3 * x3;
            }
        }
    }

#pragma unroll
    for (int nt = 0; nt < 2; ++nt) {
        float s = gsum[nt], q = gsq[nt];
        s += __shfl_xor(s, 16, 64); q += __shfl_xor(q, 16, 64);
        s += __shfl_xor(s, 32, 64); q += __shfl_xor(q, 32, 64);
        s += __shfl_xor(s, 1, 64);  q += __shfl_xor(q, 1, 64);
        s += __shfl_xor(s, 2, 64);  q += __shfl_xor(q, 2, 64);
        s += __shfl_xor(s, 4, 64);  q += __shfl_xor(q, 4, 64);
        if (lane == 0) { const int g = nt * 2;     red[wid][g * 2] = s; red[wid][g * 2 + 1] = q; }
        if (lane == 8) { const int g = nt * 2 + 1; red[wid][g * 2] = s; red[wid][g * 2 + 1] = q; }
    }
    __syncthreads();
    if (t < 8) {
        float s = 0.f;
#pragma unroll
        for (int ww8 = 0; ww8 < 8; ++ww8) s += red[ww8][t];
        atomicAdd(&stats[img * 24 + layer * 8 + t], s);
    }
}

// ---------------------------------------------------------------------------
// combine: GN2(cB [co][vox]) + GN3(skipB [vox][co]), residual add, lrelu,
// project to 16 emb ch -> embB bf16 [img][vox][16]
// ---------------------------------------------------------------------------
__global__ __launch_bounds__(256) void combine_kernel(
    const ushort* __restrict__ Bb, const ushort* __restrict__ Sk,
    const float* __restrict__ stats,
    const float* __restrict__ g2, const float* __restrict__ be2,
    const float* __restrict__ gs, const float* __restrict__ bes,
    const float* __restrict__ wp, const float* __restrict__ bp,
    ushort* __restrict__ embB)
{
    const int img = blockIdx.y;
    const int v   = blockIdx.x * 256 + threadIdx.x;
    const float Minv = 1.f / (8.f * (float)NVOX);
    float mu1[4], rs1[4], mu2[4], rs2[4];
#pragma unroll
    for (int g = 0; g < 4; ++g) {
        float s = stats[img * 24 + 8 + 2 * g], q = stats[img * 24 + 8 + 2 * g + 1];
        mu1[g] = s * Minv; rs1[g] = rsqrtf(q * Minv - mu1[g] * mu1[g] + 1e-5f);
        s = stats[img * 24 + 16 + 2 * g]; q = stats[img * 24 + 16 + 2 * g + 1];
        mu2[g] = s * Minv; rs2[g] = rsqrtf(q * Minv - mu2[g] * mu2[g] + 1e-5f);
    }
    const ushort* __restrict__ bb = Bb + (size_t)img * NB32;
    const ushort* __restrict__ sk = Sk + ((size_t)img * NVOX + v) * 32;
    float o[32];
#pragma unroll
    for (int cq = 0; cq < 4; ++cq) {
        const s8v sv8 = *reinterpret_cast<const s8v*>(sk + cq * 8);
#pragma unroll
        for (int j = 0; j < 8; ++j) {
            const int c = cq * 8 + j;
            const int g = c >> 3;
            const float hv = (bf2f(bb[c * NVOX + v]) - mu1[g]) * rs1[g] * g2[c] + be2[c];
            const float sv = (bf2f((ushort)sv8[j]) - mu2[g]) * rs2[g] * gs[c] + bes[c];
            const float tv = hv + sv;
            o[c] = tv >= 0.f ? tv : 0.2f * tv;
        }
    }
    ushort* __restrict__ eo = embB + ((size_t)img * NVOX + v) * 16;
#pragma unroll
    for (int eq = 0; eq < 2; ++eq) {
        s8v pk;
#pragma unroll
        for (int j = 0; j < 8; ++j) {
            const int e = eq * 8 + j;
            float s = bp[e];
#pragma unroll
            for (int c = 0; c < 32; ++c) s += wp[e * 32 + c] * o[c];
            pk[j] = (short)bfb(s);
        }
        *reinterpret_cast<s8v*>(eo + eq * 8) = pk;
    }
}

// ---------------------------------------------------------------------------
// attention: Q = embB[fixed][v][:], K gathered from embB[moving] (edge clamp),
// softmax over 27 neighbors, displacement = sum attn * offset (fp32 out)
// ---------------------------------------------------------------------------
__global__ __launch_bounds__(256) void attn_kernel(
    const ushort* __restrict__ embB, float* __restrict__ out)
{
    const int v = blockIdx.x * 256 + threadIdx.x;
    const int h = v >> 12, w = (v >> 6) & 63, d = v & 63;
    const ushort* __restrict__ Qp = embB + (size_t)v * 16;
    const ushort* __restrict__ Kp = embB + (size_t)NVOX * 16;
    float q[16];
    {
        const s8v q0 = *reinterpret_cast<const s8v*>(Qp);
        const s8v q1 = *reinterpret_cast<const s8v*>(Qp + 8);
#pragma unroll
        for (int j = 0; j < 8; ++j) { q[j] = bf2f((ushort)q0[j]); q[8 + j] = bf2f((ushort)q1[j]); }
    }
    float sc[27];
    float m = -1e30f;
#pragma unroll
    for (int ih = 0; ih < 3; ++ih)
#pragma unroll
    for (int iw = 0; iw < 3; ++iw)
#pragma unroll
    for (int id = 0; id < 3; ++id) {
        int hh = h + ih - 1; hh = hh < 0 ? 0 : (hh > 63 ? 63 : hh);
        int ww = w + iw - 1; ww = ww < 0 ? 0 : (ww > 63 ? 63 : ww);
        int dd = d + id - 1; dd = dd < 0 ? 0 : (dd > 63 ? 63 : dd);
        const ushort* __restrict__ kp = Kp + (size_t)((hh << 12) + (ww << 6) + dd) * 16;
        const s8v k0 = *reinterpret_cast<const s8v*>(kp);
        const s8v k1 = *reinterpret_cast<const s8v*>(kp + 8);
        float s = 0.f;
#pragma unroll
        for (int j = 0; j < 8; ++j)
            s += q[j] * bf2f((ushort)k0[j]) + q[8 + j] * bf2f((ushort)k1[j]);
        s *= 0.25f;   // / sqrt(16)
        sc[(ih * 3 + iw) * 3 + id] = s;
        m = fmaxf(m, s);
    }
    float den = 0.f;
#pragma unroll
    for (int p = 0; p < 27; ++p) { sc[p] = __expf(sc[p] - m); den += sc[p]; }
    const float inv = 1.f / den;
    float r0 = 0.f, r1 = 0.f, r2 = 0.f;
#pragma unroll
    for (int ih = 0; ih < 3; ++ih)
#pragma unroll
    for (int iw = 0; iw < 3; ++iw)
#pragma unroll
    for (int id = 0; id < 3; ++id) {
        const float a = sc[(ih * 3 + iw) * 3 + id] * inv;
        r0 += a * (float)(ih - 1);
        r1 += a * (float)(iw - 1);
        r2 += a * (float)(id - 1);
    }
    out[v]            = r0;
    out[NVOX + v]     = r1;
    out[2 * NVOX + v] = r2;
}

// ---------------------------------------------------------------------------
extern "C" void kernel_launch(void* const* d_in, const int* in_sizes, int n_in,
                              void* d_out, int out_size, void* d_ws, size_t ws_size,
                              hipStream_t stream)
{
    (void)in_sizes; (void)n_in; (void)out_size; (void)ws_size;
    const float* feat_moving = (const float*)d_in[0];
    const float* feat_fixed  = (const float*)d_in[1];
    const float* w1  = (const float*)d_in[2];
    const float* b1  = (const float*)d_in[3];
    const float* g1  = (const float*)d_in[4];
    const float* be1 = (const float*)d_in[5];
    const float* w2  = (const float*)d_in[6];
    const float* b2  = (const float*)d_in[7];
    const float* g2  = (const float*)d_in[8];
    const float* be2 = (const float*)d_in[9];
    const float* wsw = (const float*)d_in[10];
    const float* bs  = (const float*)d_in[11];
    const float* gs  = (const float*)d_in[12];
    const float* bes = (const float*)d_in[13];
    const float* wp  = (const float*)d_in[14];
    const float* bp  = (const float*)d_in[15];

    // workspace layout by lifetime (MiB offsets), max ~160.1 MiB:
    //   featB [0,32)   bf16 [vox][ci]   live tobf_skip..conv1
    //   cA    [32,64)  bf16 [co][vox]   live conv1..gn_t ; embB aliases after
    //   AB    [64,96)  bf16 [vox][ci]   live gn_t..conv2
    //   cB    [96,128) bf16 [co][vox]   live conv2..combine
    //   skipB [128,160)bf16 [vox][co]   live tobf_skip..combine
    //   embB = cA region, bf16 [img][vox][16], live combine..attn
    char* base = (char*)d_ws;
    ushort* featB = (ushort*)base;
    ushort* cA    = (ushort*)(base + (32ull << 20));
    ushort* AB    = (ushort*)(base + (64ull << 20));
    ushort* cB    = (ushort*)(base + (96ull << 20));
    ushort* skipB = (ushort*)(base + (128ull << 20));
    ushort* embB  = (ushort*)(base + (32ull << 20));
    float*  stats = (float*)(base + (160ull << 20));
    ushort* wB1   = (ushort*)(stats + 64);
    ushort* wB2   = wB1 + 27648;

    prep_kernel<<<108, 256, 0, stream>>>(w1, w2, wB1, wB2, stats);
    tobf_skip_kernel<<<dim3(1024, 2), 256, 0, stream>>>(feat_fixed, feat_moving, wsw, bs,
                                                        featB, skipB, stats);
    conv3_mfma_kernel<<<dim3(512, 2), 512, 0, stream>>>(featB, wB1, b1, cA, stats, 0);
    gn_transpose_kernel<<<dim3(1024, 2), 256, 0, stream>>>(cA, stats, g1, be1, AB);
    conv3_mfma_kernel<<<dim3(512, 2), 512, 0, stream>>>(AB, wB2, b2, cB, stats, 1);
    combine_kernel<<<dim3(1024, 2), 256, 0, stream>>>(cB, skipB, stats, g2, be2, gs, bes, wp, bp, embB);
    attn_kernel<<<1024, 256, 0, stream>>>(embB, (float*)d_out);
}

// Round 7
// 198.359 us; speedup vs baseline: 16.1551x; 1.0940x over previous
//
#include <hip/hip_runtime.h>
#include <hip/hip_bf16.h>

#define NVOX (64*64*64)      // 262144 = 2^18
#define NB32 (32*NVOX)       // 2^23 elements per image of 32-ch volume

typedef short s8v __attribute__((ext_vector_type(8)));   // 8 bf16 = 4 VGPR (MFMA A/B frag)
typedef float f4v __attribute__((ext_vector_type(4)));   // MFMA C/D frag

__device__ inline ushort bfb(float f) {
    __hip_bfloat16 h = __float2bfloat16(f);
    return *reinterpret_cast<ushort*>(&h);
}
__device__ inline float bf2f(ushort u) {
    unsigned x = (unsigned)u << 16;
    return __builtin_bit_cast(float, x);
}

// ---------------------------------------------------------------------------
// prep: conv weights [co][ci][tap] -> bf16 [tap][co][ci]; skip W -> bf16 [co][ci];
// zero stats
// ---------------------------------------------------------------------------
__global__ __launch_bounds__(256) void prep_kernel(
    const float* __restrict__ w1, const float* __restrict__ w2,
    const float* __restrict__ wsw,
    ushort* __restrict__ wB1, ushort* __restrict__ wB2,
    ushort* __restrict__ wsB, float* __restrict__ stats)
{
    if (blockIdx.x == 0 && threadIdx.x < 48) stats[threadIdx.x] = 0.f;
    int i = blockIdx.x * 256 + threadIdx.x;
    if (i < 1024) wsB[i] = bfb(wsw[i]);              // [co][ci]
    if (i < 32 * 32 * 27) {
        int co  = i / 864;            // 864 = 32*27
        int rem = i - co * 864;
        int ci  = rem / 27;
        int tap = rem - ci * 27;
        wB1[(tap * 32 + co) * 32 + ci] = bfb(w1[i]);
        wB2[(tap * 32 + co) * 32 + ci] = bfb(w2[i]);
    }
}

// ---------------------------------------------------------------------------
// fused: feat fp32 [c][vox] -> featB bf16 [vox][ci]
//        + skip 1x1 conv via MFMA -> skipB bf16 [vox][co] + GN3 stats.
// Lane (m,kc) loads vox vb+nt*16+m, ci kc*8..+8 for nt=0..3 — registers are
// directly the MFMA B-frags (col=vox, k=ci). A-frags = bf16 skip weights.
// ---------------------------------------------------------------------------
__global__ __launch_bounds__(256) void tobf_skip_kernel(
    const float* __restrict__ in0, const float* __restrict__ in1,
    const ushort* __restrict__ wsB, const float* __restrict__ bsb,
    ushort* __restrict__ featB, ushort* __restrict__ skipB,
    float* __restrict__ stats)
{
    const int img = blockIdx.y;
    const float* __restrict__ in = img ? in1 : in0;
    const int t = threadIdx.x;
    const int lane = t & 63, wid = t >> 6;
    const int m = lane & 15, kc = lane >> 4;
    const int vb = blockIdx.x * 256 + wid * 64;   // wave's vox base

    ushort* __restrict__ fo = featB + (size_t)img * NVOX * 32;

    // load + convert + store featB; keep as B-frags
    s8v bfrag[4];
#pragma unroll
    for (int nt = 0; nt < 4; ++nt) {
        const int vox = vb + nt * 16 + m;
        s8v pk;
#pragma unroll
        for (int j = 0; j < 8; ++j)
            pk[j] = (short)bfb(in[(kc * 8 + j) * NVOX + vox]);
        bfrag[nt] = pk;
        *reinterpret_cast<s8v*>(fo + (size_t)vox * 32 + kc * 8) = pk;
    }

    // skip 1x1 conv via MFMA
    const s8v* __restrict__ wv = reinterpret_cast<const s8v*>(wsB);
    const s8v a0 = wv[m * 4 + kc];          // A rows co 0..15
    const s8v a1 = wv[(m + 16) * 4 + kc];   // A rows co 16..31
    f4v acc[2][4] = {};
#pragma unroll
    for (int nt = 0; nt < 4; ++nt) {
        acc[0][nt] = __builtin_amdgcn_mfma_f32_16x16x32_bf16(a0, bfrag[nt], acc[0][nt], 0, 0, 0);
        acc[1][nt] = __builtin_amdgcn_mfma_f32_16x16x32_bf16(a1, bfrag[nt], acc[1][nt], 0, 0, 0);
    }

    // D: col = m = vox offset, row = kc*4+j (+16*mt) = co. Store [vox][co].
    ushort* __restrict__ sko = skipB + (size_t)img * NVOX * 32;
    float s0 = 0.f, q0 = 0.f, s1 = 0.f, q1 = 0.f;
#pragma unroll
    for (int mt = 0; mt < 2; ++mt) {
#pragma unroll
        for (int nt = 0; nt < 4; ++nt) {
            const f4v a = acc[mt][nt];
            ushort4 pk;
            float xs[4];
#pragma unroll
            for (int j = 0; j < 4; ++j) {
                const int co = mt * 16 + kc * 4 + j;
                xs[j] = a[j] + bsb[co];
            }
            pk.x = bfb(xs[0]); pk.y = bfb(xs[1]); pk.z = bfb(xs[2]); pk.w = bfb(xs[3]);
            *reinterpret_cast<ushort4*>(
                sko + (size_t)(vb + nt * 16 + m) * 32 + mt * 16 + kc * 4) = pk;
#pragma unroll
            for (int j = 0; j < 4; ++j) {
                if (mt == 0) { s0 += xs[j]; q0 += xs[j] * xs[j]; }
                else         { s1 += xs[j]; q1 += xs[j] * xs[j]; }
            }
        }
    }

    // reduce: lanes 0..31 hold groups {0,1} (kc 0/1 -> co 0..7 / 8..15 wait:
    // kc in {0,1} covers co 0..7? kc*4+j: kc=0 -> 0..3, kc=1 -> 4..7 => lane
    // half {kc<2} = group 0 (co 0..7), {kc>=2} = group 1 (co 8..15); mt=1 -> +2.
    __shared__ float red[4][8];
    float v4[4] = {s0, q0, s1, q1};
#pragma unroll
    for (int k = 0; k < 4; ++k) {
        float x = v4[k];
        x += __shfl_xor(x, 1, 64);
        x += __shfl_xor(x, 2, 64);
        x += __shfl_xor(x, 4, 64);
        x += __shfl_xor(x, 8, 64);
        x += __shfl_xor(x, 16, 64);
        v4[k] = x;
    }
    if (lane == 0)  { red[wid][0] = v4[0]; red[wid][1] = v4[1]; red[wid][4] = v4[2]; red[wid][5] = v4[3]; }
    if (lane == 32) { red[wid][2] = v4[0]; red[wid][3] = v4[1]; red[wid][6] = v4[2]; red[wid][7] = v4[3]; }
    __syncthreads();
    if (t < 8) {
        atomicAdd(&stats[img * 24 + 16 + t],
                  red[0][t] + red[1][t] + red[2][t] + red[3][t]);
    }
}

// ---------------------------------------------------------------------------
// GN1 apply + lrelu: cA bf16 [c][vox] -> bf16 [vox][ci]
// ---------------------------------------------------------------------------
__global__ __launch_bounds__(256) void gn_transpose_kernel(
    const ushort* __restrict__ cA, const float* __restrict__ stats,
    const float* __restrict__ gamma, const float* __restrict__ beta,
    ushort* __restrict__ outB)
{
    const int img = blockIdx.y;
    const ushort* __restrict__ in = cA + (size_t)img * NB32;
    ushort* __restrict__ op = outB + (size_t)img * NVOX * 32;
    const int v = blockIdx.x * 256 + threadIdx.x;
    const float Minv = 1.f / (8.f * (float)NVOX);
    float mu[4], rs[4];
#pragma unroll
    for (int g = 0; g < 4; ++g) {
        const float s = stats[img * 24 + 2 * g], q = stats[img * 24 + 2 * g + 1];
        mu[g] = s * Minv;
        rs[g] = rsqrtf(q * Minv - mu[g] * mu[g] + 1e-5f);
    }
#pragma unroll
    for (int ciq = 0; ciq < 4; ++ciq) {
        s8v pk;
#pragma unroll
        for (int j = 0; j < 8; ++j) {
            const int c = ciq * 8 + j;
            const int g = c >> 3;
            const float sc = rs[g] * gamma[c];
            const float sh = beta[c] - mu[g] * sc;
            float y = bf2f(in[c * NVOX + v]) * sc + sh;
            y = y >= 0.f ? y : 0.2f * y;
            pk[j] = (short)bfb(y);
        }
        *reinterpret_cast<s8v*>(op + (size_t)v * 32 + ciq * 8) = pk;
    }
}

// ---------------------------------------------------------------------------
// 3x3x3 conv 32->32 via bf16 MFMA implicit GEMM, zero pad, +bias, +GN stats.
// Input: bf16 [vox][ci]. Output: bf16 [co][vox]. Block: 512 thr (8 waves).
// LDS: 4 ci-quad planes of padded stride 1226 s8v.
// grid: (512 = 16bh x 16bw x 2bd, 2 images)
// ---------------------------------------------------------------------------
__global__ __launch_bounds__(512) void conv3_mfma_kernel(
    const ushort* __restrict__ inB,
    const ushort* __restrict__ wB, const float* __restrict__ bias,
    ushort* __restrict__ outB, float* __restrict__ stats, int layer)
{
    __shared__ __align__(16) ushort tile[4 * 1226 * 8];   // 78464 B
    __shared__ float red[8][8];

    const int img = blockIdx.y;
    const ushort* __restrict__ src = inB + (size_t)img * NVOX * 32;
    const int bx = blockIdx.x;
    const int bd = bx & 1, bw = (bx >> 1) & 15, bh = bx >> 5;
    const int t = threadIdx.x;

    // ---- stage halo tile: r = hw*34+dd (1224 rows), 4 ci-quads of 16B ----
    const int gd0 = bd * 32 - 1, gh0 = bh * 4 - 1, gw0 = bw * 4 - 1;
    s8v* __restrict__ tvw = reinterpret_cast<s8v*>(tile);
    for (int u = t; u < 4896; u += 512) {       // 1224*4
        const int r   = u >> 2;
        const int ciq = u & 3;
        const int hw = r / 34, dd = r - hw * 34;
        const int hh = hw / 6, ww = hw - hh * 6;
        const int gh = gh0 + hh, gw = gw0 + ww, gd = gd0 + dd;
        s8v val = {0, 0, 0, 0, 0, 0, 0, 0};
        if (((unsigned)gh < 64u) && ((unsigned)gw < 64u) && ((unsigned)gd < 64u))
            val = *reinterpret_cast<const s8v*>(
                src + (size_t)(((gh << 12) + (gw << 6) + gd) << 5) + (ciq << 3));
        tvw[ciq * 1226 + r] = val;
    }
    __syncthreads();

    // ---- MFMA main loop ----
    const int lane = t & 63, wid = t >> 6;
    const int m = lane & 15, kc = lane >> 4;
    const int hp = wid & 3, wh = wid >> 2;

    int pre8[2][2];   // A-frag row base per (w' = wh*2+i2, d-subtile dt)
#pragma unroll
    for (int i2 = 0; i2 < 2; ++i2)
#pragma unroll
    for (int dt = 0; dt < 2; ++dt)
        pre8[i2][dt] = kc * 1226 + (hp * 6 + wh * 2 + i2) * 34 + dt * 16 + m;

    const int wlane = m * 4 + kc;   // B-frag s8v offset within a tap
    const s8v* __restrict__ tv = reinterpret_cast<const s8v*>(tile);
    const s8v* __restrict__ wv = reinterpret_cast<const s8v*>(wB);

    f4v acc[2][2][2] = {};
#pragma unroll
    for (int tap = 0; tap < 27; ++tap) {
        const int dh = tap / 9, dw = (tap / 3) % 3, dd = tap % 3;
        const int toff = (dh * 6 + dw) * 34 + dd;
        const s8v bf0 = wv[tap * 128 + wlane];        // co = m
        const s8v bf1 = wv[tap * 128 + 64 + wlane];   // co = m+16
#pragma unroll
        for (int i2 = 0; i2 < 2; ++i2)
#pragma unroll
        for (int dt = 0; dt < 2; ++dt) {
            const s8v a = tv[pre8[i2][dt] + toff];
            acc[i2][dt][0] = __builtin_amdgcn_mfma_f32_16x16x32_bf16(a, bf0, acc[i2][dt][0], 0, 0, 0);
            acc[i2][dt][1] = __builtin_amdgcn_mfma_f32_16x16x32_bf16(a, bf1, acc[i2][dt][1], 0, 0, 0);
        }
    }

    // ---- epilogue: +bias, bf16 ushort4 store along d, GN stats (fp32) ----
    ushort* __restrict__ outi = outB + (size_t)img * NB32;
    const float b0 = bias[m], b1 = bias[m + 16];
    ushort* __restrict__ op0 = outi + (size_t)m * NVOX;           // co = m
    ushort* __restrict__ op1 = outi + (size_t)(m + 16) * NVOX;    // co = m+16
    float gsum[2] = {0.f, 0.f}, gsq[2] = {0.f, 0.f};
#pragma unroll
    for (int i2 = 0; i2 < 2; ++i2) {
#pragma unroll
        for (int dt = 0; dt < 2; ++dt) {
            const int v = ((bh * 4 + hp) << 12) + ((bw * 4 + wh * 2 + i2) << 6)
                        + bd * 32 + dt * 16 + kc * 4;
#pragma unroll
            for (int nt = 0; nt < 2; ++nt) {
                const f4v a = acc[i2][dt][nt];
                const float bb = nt ? b1 : b0;
                const float x0 = a[0] + bb, x1 = a[1] + bb, x2 = a[2] + bb, x3 = a[3] + bb;
                ushort4 pk;
                pk.x = bfb(x0); pk.y = bfb(x1); pk.z = bfb(x2); pk.w = bfb(x3);
                *reinterpret_cast<ushort4*>((nt ? op1 : op0) + v) = pk;
                gsum[nt] += x0 + x1 + x2 + x3;
                gsq[nt]  += x0 * x0 + x1 * x1 + x2 * x2 + x3 * x3;
            }
        }
    }

#pragma unroll
    for (int nt = 0; nt < 2; ++nt) {
        float s = gsum[nt], q = gsq[nt];
        s += __shfl_xor(s, 16, 64); q += __shfl_xor(q, 16, 64);
        s += __shfl_xor(s, 32, 64); q += __shfl_xor(q, 32, 64);
        s += __shfl_xor(s, 1, 64);  q += __shfl_xor(q, 1, 64);
        s += __shfl_xor(s, 2, 64);  q += __shfl_xor(q, 2, 64);
        s += __shfl_xor(s, 4, 64);  q += __shfl_xor(q, 4, 64);
        if (lane == 0) { const int g = nt * 2;     red[wid][g * 2] = s; red[wid][g * 2 + 1] = q; }
        if (lane == 8) { const int g = nt * 2 + 1; red[wid][g * 2] = s; red[wid][g * 2 + 1] = q; }
    }
    __syncthreads();
    if (t < 8) {
        float s = 0.f;
#pragma unroll
        for (int ww8 = 0; ww8 < 8; ++ww8) s += red[ww8][t];
        atomicAdd(&stats[img * 24 + layer * 8 + t], s);
    }
}

// ---------------------------------------------------------------------------
// combine: GN2(cB [co][vox]) + GN3(skipB [vox][co]), residual add, lrelu,
// project to 16 emb ch -> embB bf16 [img][vox][16]
// ---------------------------------------------------------------------------
__global__ __launch_bounds__(256) void combine_kernel(
    const ushort* __restrict__ Bb, const ushort* __restrict__ Sk,
    const float* __restrict__ stats,
    const float* __restrict__ g2, const float* __restrict__ be2,
    const float* __restrict__ gs, const float* __restrict__ bes,
    const float* __restrict__ wp, const float* __restrict__ bp,
    ushort* __restrict__ embB)
{
    const int img = blockIdx.y;
    const int v   = blockIdx.x * 256 + threadIdx.x;
    const float Minv = 1.f / (8.f * (float)NVOX);
    float mu1[4], rs1[4], mu2[4], rs2[4];
#pragma unroll
    for (int g = 0; g < 4; ++g) {
        float s = stats[img * 24 + 8 + 2 * g], q = stats[img * 24 + 8 + 2 * g + 1];
        mu1[g] = s * Minv; rs1[g] = rsqrtf(q * Minv - mu1[g] * mu1[g] + 1e-5f);
        s = stats[img * 24 + 16 + 2 * g]; q = stats[img * 24 + 16 + 2 * g + 1];
        mu2[g] = s * Minv; rs2[g] = rsqrtf(q * Minv - mu2[g] * mu2[g] + 1e-5f);
    }
    const ushort* __restrict__ bb = Bb + (size_t)img * NB32;
    const ushort* __restrict__ sk = Sk + ((size_t)img * NVOX + v) * 32;
    float o[32];
#pragma unroll
    for (int cq = 0; cq < 4; ++cq) {
        const s8v sv8 = *reinterpret_cast<const s8v*>(sk + cq * 8);
#pragma unroll
        for (int j = 0; j < 8; ++j) {
            const int c = cq * 8 + j;
            const int g = c >> 3;
            const float hv = (bf2f(bb[c * NVOX + v]) - mu1[g]) * rs1[g] * g2[c] + be2[c];
            const float sv = (bf2f((ushort)sv8[j]) - mu2[g]) * rs2[g] * gs[c] + bes[c];
            const float tv = hv + sv;
            o[c] = tv >= 0.f ? tv : 0.2f * tv;
        }
    }
    ushort* __restrict__ eo = embB + ((size_t)img * NVOX + v) * 16;
#pragma unroll
    for (int eq = 0; eq < 2; ++eq) {
        s8v pk;
#pragma unroll
        for (int j = 0; j < 8; ++j) {
            const int e = eq * 8 + j;
            float s = bp[e];
#pragma unroll
            for (int c = 0; c < 32; ++c) s += wp[e * 32 + c] * o[c];
            pk[j] = (short)bfb(s);
        }
        *reinterpret_cast<s8v*>(eo + eq * 8) = pk;
    }
}

// ---------------------------------------------------------------------------
// attention: Q = embB[fixed][v][:], K gathered from embB[moving] (edge clamp),
// softmax over 27 neighbors, displacement = sum attn * offset (fp32 out)
// ---------------------------------------------------------------------------
__global__ __launch_bounds__(256) void attn_kernel(
    const ushort* __restrict__ embB, float* __restrict__ out)
{
    const int v = blockIdx.x * 256 + threadIdx.x;
    const int h = v >> 12, w = (v >> 6) & 63, d = v & 63;
    const ushort* __restrict__ Qp = embB + (size_t)v * 16;
    const ushort* __restrict__ Kp = embB + (size_t)NVOX * 16;
    float q[16];
    {
        const s8v q0 = *reinterpret_cast<const s8v*>(Qp);
        const s8v q1 = *reinterpret_cast<const s8v*>(Qp + 8);
#pragma unroll
        for (int j = 0; j < 8; ++j) { q[j] = bf2f((ushort)q0[j]); q[8 + j] = bf2f((ushort)q1[j]); }
    }
    float sc[27];
    float m = -1e30f;
#pragma unroll
    for (int ih = 0; ih < 3; ++ih)
#pragma unroll
    for (int iw = 0; iw < 3; ++iw)
#pragma unroll
    for (int id = 0; id < 3; ++id) {
        int hh = h + ih - 1; hh = hh < 0 ? 0 : (hh > 63 ? 63 : hh);
        int ww = w + iw - 1; ww = ww < 0 ? 0 : (ww > 63 ? 63 : ww);
        int dd = d + id - 1; dd = dd < 0 ? 0 : (dd > 63 ? 63 : dd);
        const ushort* __restrict__ kp = Kp + (size_t)((hh << 12) + (ww << 6) + dd) * 16;
        const s8v k0 = *reinterpret_cast<const s8v*>(kp);
        const s8v k1 = *reinterpret_cast<const s8v*>(kp + 8);
        float s = 0.f;
#pragma unroll
        for (int j = 0; j < 8; ++j)
            s += q[j] * bf2f((ushort)k0[j]) + q[8 + j] * bf2f((ushort)k1[j]);
        s *= 0.25f;   // / sqrt(16)
        sc[(ih * 3 + iw) * 3 + id] = s;
        m = fmaxf(m, s);
    }
    float den = 0.f;
#pragma unroll
    for (int p = 0; p < 27; ++p) { sc[p] = __expf(sc[p] - m); den += sc[p]; }
    const float inv = 1.f / den;
    float r0 = 0.f, r1 = 0.f, r2 = 0.f;
#pragma unroll
    for (int ih = 0; ih < 3; ++ih)
#pragma unroll
    for (int iw = 0; iw < 3; ++iw)
#pragma unroll
    for (int id = 0; id < 3; ++id) {
        const float a = sc[(ih * 3 + iw) * 3 + id] * inv;
        r0 += a * (float)(ih - 1);
        r1 += a * (float)(iw - 1);
        r2 += a * (float)(id - 1);
    }
    out[v]            = r0;
    out[NVOX + v]     = r1;
    out[2 * NVOX + v] = r2;
}

// ---------------------------------------------------------------------------
extern "C" void kernel_launch(void* const* d_in, const int* in_sizes, int n_in,
                              void* d_out, int out_size, void* d_ws, size_t ws_size,
                              hipStream_t stream)
{
    (void)in_sizes; (void)n_in; (void)out_size; (void)ws_size;
    const float* feat_moving = (const float*)d_in[0];
    const float* feat_fixed  = (const float*)d_in[1];
    const float* w1  = (const float*)d_in[2];
    const float* b1  = (const float*)d_in[3];
    const float* g1  = (const float*)d_in[4];
    const float* be1 = (const float*)d_in[5];
    const float* w2  = (const float*)d_in[6];
    const float* b2  = (const float*)d_in[7];
    const float* g2  = (const float*)d_in[8];
    const float* be2 = (const float*)d_in[9];
    const float* wsw = (const float*)d_in[10];
    const float* bs  = (const float*)d_in[11];
    const float* gs  = (const float*)d_in[12];
    const float* bes = (const float*)d_in[13];
    const float* wp  = (const float*)d_in[14];
    const float* bp  = (const float*)d_in[15];

    // workspace layout by lifetime (MiB offsets), max ~160.1 MiB:
    //   featB [0,32)   bf16 [vox][ci]   live tobf_skip..conv1
    //   cA    [32,64)  bf16 [co][vox]   live conv1..gn_t ; embB aliases after
    //   AB    [64,96)  bf16 [vox][ci]   live gn_t..conv2
    //   cB    [96,128) bf16 [co][vox]   live conv2..combine
    //   skipB [128,160)bf16 [vox][co]   live tobf_skip..combine
    //   embB = cA region, bf16 [img][vox][16], live combine..attn
    char* base = (char*)d_ws;
    ushort* featB = (ushort*)base;
    ushort* cA    = (ushort*)(base + (32ull << 20));
    ushort* AB    = (ushort*)(base + (64ull << 20));
    ushort* cB    = (ushort*)(base + (96ull << 20));
    ushort* skipB = (ushort*)(base + (128ull << 20));
    ushort* embB  = (ushort*)(base + (32ull << 20));
    float*  stats = (float*)(base + (160ull << 20));
    ushort* wB1   = (ushort*)(stats + 64);
    ushort* wB2   = wB1 + 27648;
    ushort* wsB   = wB2 + 27648;

    prep_kernel<<<108, 256, 0, stream>>>(w1, w2, wsw, wB1, wB2, wsB, stats);
    tobf_skip_kernel<<<dim3(1024, 2), 256, 0, stream>>>(feat_fixed, feat_moving, wsB, bs,
                                                        featB, skipB, stats);
    conv3_mfma_kernel<<<dim3(512, 2), 512, 0, stream>>>(featB, wB1, b1, cA, stats, 0);
    gn_transpose_kernel<<<dim3(1024, 2), 256, 0, stream>>>(cA, stats, g1, be1, AB);
    conv3_mfma_kernel<<<dim3(512, 2), 512, 0, stream>>>(AB, wB2, b2, cB, stats, 1);
    combine_kernel<<<dim3(1024, 2), 256, 0, stream>>>(cB, skipB, stats, g2, be2, gs, bes, wp, bp, embB);
    attn_kernel<<<1024, 256, 0, stream>>>(embB, (float*)d_out);
}